// Round 3
// baseline (716.070 us; speedup 1.0000x reference)
//
#include <hip/hip_runtime.h>
#include <hip/hip_bf16.h>

// Problem constants (GatedDeltaNet: B=2, T=1024, D=2048, HK=8, HV=16, DK=DV=128, KW=4)
#define B_ 2
#define T_ 1024
#define D_ 2048
#define HK_ 8
#define HV_ 16
#define DK_ 128
#define DV_ 128
#define KEY_DIM_ 1024
#define VALUE_DIM_ 2048
#define CONV_DIM_ 4096
#define BT_ 2048   // B*T

typedef __attribute__((ext_vector_type(8))) short short8;
typedef __attribute__((ext_vector_type(4))) float f32x4;

__device__ __forceinline__ short f2bf(float x) {
  __hip_bfloat16 h = __float2bfloat16(x);
  return *reinterpret_cast<short*>(&h);
}

// async global->LDS, 16B per lane (m97 path). LDS dest must be wave-uniform
// base + lane*16 — our staging layout satisfies this (tid*16B, unpadded).
#define GLOAD_LDS16(g, l)                                             \
  __builtin_amdgcn_global_load_lds(                                   \
      (const __attribute__((address_space(1))) void*)(g),             \
      (__attribute__((address_space(3))) void*)(l), 16, 0, 0)

// DPP-based add within a 16-lane row (VALU pipe, no LDS).
template <int CTRL>
__device__ __forceinline__ float dpp_add(float x) {
  int r = __builtin_amdgcn_update_dpp(0, __float_as_int(x), CTRL, 0xF, 0xF, true);
  return x + __int_as_float(r);
}
// sum across a 32-lane group (lanes grouped as two 16-rows), result in all 32:
__device__ __forceinline__ float row32_sum(float x) {
  x = dpp_add<0xB1>(x);    // quad_perm xor1
  x = dpp_add<0x4E>(x);    // quad_perm xor2
  x = dpp_add<0x124>(x);   // row_ror:4
  x = dpp_add<0x128>(x);   // row_ror:8  -> each 16-row has its sum
  x += __shfl_xor(x, 16, 32);  // combine the two 16-rows
  return x;
}

// ---------------- cast f32 -> bf16 (vectorized) ----------------
__global__ void cast_plain(const float* __restrict__ in, short* __restrict__ out, int n4) {
  int i = blockIdx.x * blockDim.x + threadIdx.x;
  if (i < n4) {
    float4 v = ((const float4*)in)[i];
    short4 o;
    o.x = f2bf(v.x); o.y = f2bf(v.y); o.z = f2bf(v.z); o.w = f2bf(v.w);
    ((short4*)out)[i] = o;
  }
}

// ---------------- transpose + cast: W[R,C] f32 -> WT[C,R] bf16 ----------------
__global__ void transpose_cast(const float* __restrict__ W, short* __restrict__ WT, int R, int C) {
  __shared__ float tile[32][33];
  int tx = threadIdx.x, ty = threadIdx.y;
  int x = blockIdx.x * 32 + tx;
#pragma unroll
  for (int j = 0; j < 4; ++j) {
    int r = blockIdx.y * 32 + ty + j * 8;
    tile[ty + j * 8][tx] = W[(long)r * C + x];
  }
  __syncthreads();
  int ro = blockIdx.y * 32 + tx;
#pragma unroll
  for (int j = 0; j < 4; ++j) {
    int co = blockIdx.x * 32 + ty + j * 8;
    WT[(long)co * R + ro] = f2bf(tile[tx][ty + j * 8]);
  }
}

// ---------------- W_b|W_a -> WbaT[32][D] (contiguous rows for small_proj) ----
__global__ void transpose_ba(const float* __restrict__ Wb, const float* __restrict__ Wa,
                             float* __restrict__ WbaT) {
  int i = blockIdx.x * 256 + threadIdx.x;   // 32*D total
  int c = i & 31, r = i >> 5;
  float v = (c < 16) ? Wb[r * 16 + c] : Wa[r * 16 + (c - 16)];
  WbaT[c * D_ + r] = v;
}

// ---------------- bf16 MFMA GEMM: C[M,N] f32 = A[M,K] * Bt[N,K]^T ----------------
// m97 structure: global_load_lds width-16 staging, unpadded LDS, 2-barrier K-loop.
__global__ __launch_bounds__(256) void gemm128(const short* __restrict__ A,
                                               const short* __restrict__ Bt,
                                               float* __restrict__ C,
                                               int M, int N, int K) {
  __shared__ short As[128 * 32];
  __shared__ short Bs[128 * 32];
  int m0 = blockIdx.y * 128, n0 = blockIdx.x * 128;
  int tid = threadIdx.x;
  int wave = tid >> 6, lane = tid & 63;
  int wm = (wave >> 1) * 64, wn = (wave & 1) * 64;
  int quad = lane >> 4, l16 = lane & 15;
  f32x4 acc[4][4] = {};

  int ar = tid >> 2;            // 0..63
  int ac = (tid & 3) * 8;       // 0,8,16,24
  const short* Ag0 = A + (long)(m0 + ar) * K + ac;
  const short* Ag1 = A + (long)(m0 + 64 + ar) * K + ac;
  const short* Bg0 = Bt + (long)(n0 + ar) * K + ac;
  const short* Bg1 = Bt + (long)(n0 + 64 + ar) * K + ac;
  short* lA0 = As + tid * 8;            // byte offset tid*16 = wave*1024 + lane*16
  short* lA1 = As + 64 * 32 + tid * 8;
  short* lB0 = Bs + tid * 8;
  short* lB1 = Bs + 64 * 32 + tid * 8;

  for (int k0 = 0; k0 < K; k0 += 32) {
    GLOAD_LDS16(Ag0 + k0, lA0);
    GLOAD_LDS16(Ag1 + k0, lA1);
    GLOAD_LDS16(Bg0 + k0, lB0);
    GLOAD_LDS16(Bg1 + k0, lB1);
    __syncthreads();   // drains vmcnt -> staged data visible to all

    short8 af[4], bf_[4];
#pragma unroll
    for (int i = 0; i < 4; ++i) af[i] = *(const short8*)(As + (wm + i * 16 + l16) * 32 + quad * 8);
#pragma unroll
    for (int j = 0; j < 4; ++j) bf_[j] = *(const short8*)(Bs + (wn + j * 16 + l16) * 32 + quad * 8);
#pragma unroll
    for (int i = 0; i < 4; ++i)
#pragma unroll
      for (int j = 0; j < 4; ++j)
        acc[i][j] = __builtin_amdgcn_mfma_f32_16x16x32_bf16(af[i], bf_[j], acc[i][j], 0, 0, 0);
    __syncthreads();   // all frag reads done before next overwrite
  }

#pragma unroll
  for (int i = 0; i < 4; ++i)
#pragma unroll
    for (int j = 0; j < 4; ++j)
#pragma unroll
      for (int r = 0; r < 4; ++r) {
        int row = m0 + wm + i * 16 + quad * 4 + r;
        int colx = n0 + wn + j * 16 + l16;
        C[(long)row * N + colx] = acc[i][j][r];
      }
}

// ---------------- beta / exp(g) projections (fp32, contiguous W reads) -------
__global__ __launch_bounds__(256) void small_proj(const float* __restrict__ hidden,
                                                  const float* __restrict__ WbaT,
                                                  const float* __restrict__ dt_bias,
                                                  const float* __restrict__ A_log,
                                                  float* __restrict__ betaT,
                                                  float* __restrict__ egT) {
  __shared__ float red[256];
  int r = blockIdx.x;                     // row in [0, B*T)
  int tid = threadIdx.x;
  int h = tid & 31;                       // 0..15 -> W_b col, 16..31 -> W_a col
  int s = tid >> 5;                       // 0..7 K-slice
  const float4* hp = (const float4*)(hidden + (long)r * D_ + s * 256);
  const float4* wp = (const float4*)(WbaT + (long)h * D_ + s * 256);
  float acc = 0.f;
#pragma unroll 8
  for (int i = 0; i < 64; ++i) {
    float4 a = hp[i], w = wp[i];
    acc += a.x * w.x + a.y * w.y + a.z * w.z + a.w * w.w;
  }
  red[tid] = acc;
  __syncthreads();
  if (tid < 32) {
    float t = 0.f;
#pragma unroll
    for (int ss = 0; ss < 8; ++ss) t += red[ss * 32 + tid];
    if (tid < 16) {
      betaT[tid * BT_ + r] = 1.f / (1.f + __expf(-t));
    } else {
      int hh = tid - 16;
      float y = t + dt_bias[hh];
      float sp = fmaxf(y, 0.f) + log1pf(__expf(-fabsf(y)));  // stable softplus
      egT[hh * BT_ + r] = __expf(-__expf(A_log[hh]) * sp);   // exp(g) precomputed
    }
  }
}

// ---------------- depthwise causal conv (K=4) + SiLU ----------------
__global__ void conv_silu(const float* __restrict__ x, const float* __restrict__ w,
                          float* __restrict__ y) {
  int idx = blockIdx.x * 256 + threadIdx.x;     // B*T*CONV_DIM
  int c = idx & (CONV_DIM_ - 1);
  int bt = idx >> 12;
  int t = bt & (T_ - 1);
  float4 wc = *(const float4*)(w + c * 4);
  const float* xp = x + (long)idx;
  float acc = wc.w * xp[0];
  if (t >= 1) acc += wc.z * xp[-CONV_DIM_];
  if (t >= 2) acc += wc.y * xp[-2 * CONV_DIM_];
  if (t >= 3) acc += wc.x * xp[-3 * CONV_DIM_];
  y[idx] = acc * (1.f / (1.f + __expf(-acc)));
}

// ---------------- q/k l2norm (+ q scale) ----------------
__global__ __launch_bounds__(64) void qknorm(const float* __restrict__ qkv,
                                             float* __restrict__ qn, float* __restrict__ kn) {
  int bi = blockIdx.x;          // B*T*HK*2
  int which = bi & 1;           // 0=q, 1=k
  int h = (bi >> 1) & 7;
  int bt = bi >> 4;
  int lane = threadIdx.x;
  const float* src = qkv + (long)bt * CONV_DIM_ + which * KEY_DIM_ + h * DK_;
  float2 v = *(const float2*)(src + lane * 2);
  float ss = v.x * v.x + v.y * v.y;
#pragma unroll
  for (int m = 32; m; m >>= 1) ss += __shfl_xor(ss, m, 64);
  float scale = rsqrtf(ss + 1e-6f);
  if (which == 0) scale *= 0.08838834764831845f;  // DK^-0.5
  float* dst = (which ? kn : qn) + ((long)bt * HK_ + h) * DK_;
  float2 o; o.x = v.x * scale; o.y = v.y * scale;
  ((float2*)dst)[lane] = o;
}

// ---------------- gated delta-rule scan ----------------
// grid: 512 blocks = (b, hv, 8-col group); block: 256 threads = 8 cols x 32 kt.
// Each thread holds 4 state rows of one v-column. 2 waves/SIMD co-resident.
__global__ __launch_bounds__(256, 2) void scan_kernel(const float* __restrict__ qn,
                                                      const float* __restrict__ kn,
                                                      const float* __restrict__ qkv,
                                                      const float* __restrict__ egT,
                                                      const float* __restrict__ bT,
                                                      float* __restrict__ obuf) {
  int bi = blockIdx.x;
  int oct = bi & 15, hv = (bi >> 4) & 15, b = bi >> 8;
  int hk = hv >> 1;  // GQA repeat_interleave: expanded head j -> source j/2
  int tid = threadIdx.x;
  int kt = tid & 31, vg = tid >> 5;
  int col = oct * 8 + vg;

  const float* kp = kn + ((long)(b * T_) * HK_ + hk) * DK_ + kt * 4;
  const float* qp = qn + ((long)(b * T_) * HK_ + hk) * DK_ + kt * 4;
  const float* vp = qkv + (long)(b * T_) * CONV_DIM_ + 2 * KEY_DIM_ + hv * DV_ + col;
  const float* gp = egT + (hv * B_ + b) * T_;
  const float* bp = bT + (hv * B_ + b) * T_;
  float* op = obuf + ((long)(b * T_) * HV_ + hv) * DV_ + col;

  const int kstep = HK_ * DK_;    // 1024 floats per t
  const int vstep = CONV_DIM_;    // 4096

  float S[4] = {0, 0, 0, 0};

  // 4-deep rotating prefetch buffers
  float4 KA[4], QA[4];
  float V[4], G[4], Bb[4];
#pragma unroll
  for (int j = 0; j < 4; ++j) {
    KA[j] = *(const float4*)(kp + (long)j * kstep);
    QA[j] = *(const float4*)(qp + (long)j * kstep);
    V[j]  = vp[(long)j * vstep];
    G[j]  = gp[j];
    Bb[j] = bp[j];
  }

  for (int t = 0; t < T_; t += 4) {
#pragma unroll
    for (int j = 0; j < 4; ++j) {
      int tc = t + j;
      float4 ka = KA[j], qa = QA[j];
      float vv = V[j], eg = G[j], bb = Bb[j];
      int tn = tc + 4; if (tn > T_ - 1) tn = T_ - 1;
      KA[j] = *(const float4*)(kp + (long)tn * kstep);
      QA[j] = *(const float4*)(qp + (long)tn * kstep);
      V[j]  = vp[(long)tn * vstep];
      G[j]  = gp[tn];
      Bb[j] = bp[tn];

      // three dots on S_old (treed; q-dots run parallel to the critical chain)
      float pk  = (ka.x * S[0] + ka.y * S[1]) + (ka.z * S[2] + ka.w * S[3]);
      float pq  = (qa.x * S[0] + qa.y * S[1]) + (qa.z * S[2] + qa.w * S[3]);
      float pqk = (qa.x * ka.x + qa.y * ka.y) + (qa.z * ka.z + qa.w * ka.w);
      pk = row32_sum(pk);
      float vadj = (vv - eg * pk) * bb;
      S[0] = S[0] * eg + ka.x * vadj;
      S[1] = S[1] * eg + ka.y * vadj;
      S[2] = S[2] * eg + ka.z * vadj;
      S[3] = S[3] * eg + ka.w * vadj;
      pq = row32_sum(pq);    // off the recurrence critical path
      pqk = row32_sum(pqk);
      float o = eg * pq + pqk * vadj;   // q.S_new = eg*(q.S_old) + (q.k)*vadj
      if (kt == 0) op[(long)tc * VALUE_DIM_] = o;
    }
  }
}

// ---------------- gated RMSNorm * silu(z), cast to bf16 ----------------
__global__ __launch_bounds__(64) void rms_gate(const float* __restrict__ obuf,
                                               const float* __restrict__ zbuf,
                                               const float* __restrict__ nw,
                                               short* __restrict__ obf) {
  int bi = blockIdx.x;          // B*T*HV
  int hv = bi & 15;
  int bt = bi >> 4;
  int lane = threadIdx.x;
  const float* o = obuf + ((long)bt * HV_ + hv) * DV_;
  float2 ov = *(const float2*)(o + lane * 2);
  float ss = ov.x * ov.x + ov.y * ov.y;
#pragma unroll
  for (int m = 32; m; m >>= 1) ss += __shfl_xor(ss, m, 64);
  float scale = rsqrtf(ss * (1.f / 128.f) + 1e-6f);
  float2 wv = *(const float2*)(nw + lane * 2);
  const float* z = zbuf + (long)bt * VALUE_DIM_ + hv * DV_;
  float2 zv = *(const float2*)(z + lane * 2);
  float s0 = zv.x * (1.f / (1.f + __expf(-zv.x)));
  float s1 = zv.y * (1.f / (1.f + __expf(-zv.y)));
  short2 r;
  r.x = f2bf(ov.x * scale * wv.x * s0);
  r.y = f2bf(ov.y * scale * wv.y * s1);
  ((short2*)(obf + ((long)bt * VALUE_DIM_ + hv * DV_)))[lane] = r;
}

// ---------------- launcher ----------------
extern "C" void kernel_launch(void* const* d_in, const int* in_sizes, int n_in,
                              void* d_out, int out_size, void* d_ws, size_t ws_size,
                              hipStream_t stream) {
  const float* hidden  = (const float*)d_in[0];
  const float* W_qkv   = (const float*)d_in[1];
  const float* W_z     = (const float*)d_in[2];
  const float* W_b     = (const float*)d_in[3];
  const float* W_a     = (const float*)d_in[4];
  const float* conv_w  = (const float*)d_in[5];
  const float* dt_bias = (const float*)d_in[6];
  const float* A_log   = (const float*)d_in[7];
  const float* norm_w  = (const float*)d_in[8];
  const float* W_out   = (const float*)d_in[9];
  float* out = (float*)d_out;

  char* ws = (char*)d_ws;
  size_t off = 0;
  auto alloc = [&](size_t bytes) {
    void* p = ws + off;
    off += (bytes + 255) & ~(size_t)255;
    return p;
  };
  short* hidden_bf = (short*)alloc((size_t)BT_ * D_ * 2);          // 8 MB
  short* WqkvT     = (short*)alloc((size_t)CONV_DIM_ * D_ * 2);    // 16 MB
  short* WzT       = (short*)alloc((size_t)VALUE_DIM_ * D_ * 2);   // 8 MB
  short* WoutT     = (short*)alloc((size_t)D_ * VALUE_DIM_ * 2);   // 8 MB
  float* mixed     = (float*)alloc((size_t)BT_ * CONV_DIM_ * 4);   // 32 MB
  float* qkv       = (float*)alloc((size_t)BT_ * CONV_DIM_ * 4);   // 32 MB
  float* zbuf      = (float*)alloc((size_t)BT_ * VALUE_DIM_ * 4);  // 16 MB
  float* qn        = (float*)alloc((size_t)BT_ * KEY_DIM_ * 4);    // 8 MB
  float* kn        = (float*)alloc((size_t)BT_ * KEY_DIM_ * 4);    // 8 MB
  float* betab     = (float*)alloc((size_t)BT_ * HV_ * 4);
  float* gb        = (float*)alloc((size_t)BT_ * HV_ * 4);
  float* WbaT      = (float*)alloc((size_t)32 * D_ * 4);           // 256 KB
  float* obuf = mixed;       // alias: mixed dead after conv_silu
  short* obf  = hidden_bf;   // alias: hidden_bf dead after gemm(z)

  dim3 tb32(32, 8);
  cast_plain<<<(BT_ * D_ / 4 + 255) / 256, 256, 0, stream>>>(hidden, hidden_bf, BT_ * D_ / 4);
  transpose_cast<<<dim3(CONV_DIM_ / 32, D_ / 32), tb32, 0, stream>>>(W_qkv, WqkvT, D_, CONV_DIM_);
  transpose_cast<<<dim3(VALUE_DIM_ / 32, D_ / 32), tb32, 0, stream>>>(W_z, WzT, D_, VALUE_DIM_);
  transpose_cast<<<dim3(D_ / 32, VALUE_DIM_ / 32), tb32, 0, stream>>>(W_out, WoutT, VALUE_DIM_, D_);
  transpose_ba<<<32 * D_ / 256, 256, 0, stream>>>(W_b, W_a, WbaT);

  gemm128<<<dim3(CONV_DIM_ / 128, BT_ / 128), 256, 0, stream>>>(hidden_bf, WqkvT, mixed, BT_, CONV_DIM_, D_);
  gemm128<<<dim3(VALUE_DIM_ / 128, BT_ / 128), 256, 0, stream>>>(hidden_bf, WzT, zbuf, BT_, VALUE_DIM_, D_);
  small_proj<<<BT_, 256, 0, stream>>>(hidden, WbaT, dt_bias, A_log, betab, gb);
  conv_silu<<<BT_ * CONV_DIM_ / 256, 256, 0, stream>>>(mixed, conv_w, qkv);
  qknorm<<<BT_ * HK_ * 2, 64, 0, stream>>>(qkv, qn, kn);
  scan_kernel<<<512, 256, 0, stream>>>(qn, kn, qkv, gb, betab, obuf);
  rms_gate<<<BT_ * HV_, 64, 0, stream>>>(obuf, zbuf, norm_w, obf);
  gemm128<<<dim3(D_ / 128, BT_ / 128), 256, 0, stream>>>(obf, WoutT, out, BT_, D_, VALUE_DIM_);
}

// Round 4
// 609.887 us; speedup vs baseline: 1.1741x; 1.1741x over previous
//
#include <hip/hip_runtime.h>
#include <hip/hip_bf16.h>

// GatedDeltaNet: B=2, T=1024, D=2048, HK=8, HV=16, DK=DV=128, KW=4
#define B_ 2
#define T_ 1024
#define D_ 2048
#define HK_ 8
#define HV_ 16
#define DK_ 128
#define DV_ 128
#define KEY_DIM_ 1024
#define VALUE_DIM_ 2048
#define CONV_DIM_ 4096
#define BT_ 2048   // B*T
#define NCH_ 16    // chunks per sequence (T/64)
#define CL_ 64     // chunk length

typedef __attribute__((ext_vector_type(8))) short short8;
typedef __attribute__((ext_vector_type(4))) float f32x4;

__device__ __forceinline__ short f2bf(float x) {
  __hip_bfloat16 h = __float2bfloat16(x);
  return *reinterpret_cast<short*>(&h);
}
__device__ __forceinline__ float bf2f(short u) {
  unsigned int x = ((unsigned int)(unsigned short)u) << 16;
  return __int_as_float(x);
}

#define GLOAD_LDS16(g, l)                                             \
  __builtin_amdgcn_global_load_lds(                                   \
      (const __attribute__((address_space(1))) void*)(g),             \
      (__attribute__((address_space(3))) void*)(l), 16, 0, 0)

// ---------------- cast f32 -> bf16 ----------------
__global__ void cast_plain(const float* __restrict__ in, short* __restrict__ out, int n4) {
  int i = blockIdx.x * blockDim.x + threadIdx.x;
  if (i < n4) {
    float4 v = ((const float4*)in)[i];
    short4 o;
    o.x = f2bf(v.x); o.y = f2bf(v.y); o.z = f2bf(v.z); o.w = f2bf(v.w);
    ((short4*)out)[i] = o;
  }
}

// ---------------- transpose + cast: W[R,C] f32 -> WT[C,R] bf16 ----------------
__global__ void transpose_cast(const float* __restrict__ W, short* __restrict__ WT, int R, int C) {
  __shared__ float tile[32][33];
  int tx = threadIdx.x, ty = threadIdx.y;
  int x = blockIdx.x * 32 + tx;
#pragma unroll
  for (int j = 0; j < 4; ++j) {
    int r = blockIdx.y * 32 + ty + j * 8;
    tile[ty + j * 8][tx] = W[(long)r * C + x];
  }
  __syncthreads();
  int ro = blockIdx.y * 32 + tx;
#pragma unroll
  for (int j = 0; j < 4; ++j) {
    int co = blockIdx.x * 32 + ty + j * 8;
    WT[(long)co * R + ro] = f2bf(tile[tx][ty + j * 8]);
  }
}

// ---------------- W_b|W_a -> WbaT[32][D] ----------------
__global__ void transpose_ba(const float* __restrict__ Wb, const float* __restrict__ Wa,
                             float* __restrict__ WbaT) {
  int i = blockIdx.x * 256 + threadIdx.x;
  int c = i & 31, r = i >> 5;
  float v = (c < 16) ? Wb[r * 16 + c] : Wa[r * 16 + (c - 16)];
  WbaT[c * D_ + r] = v;
}

// ---------------- bf16 MFMA GEMM (m97-style) ----------------
__global__ __launch_bounds__(256) void gemm128(const short* __restrict__ A,
                                               const short* __restrict__ Bt,
                                               float* __restrict__ C,
                                               int M, int N, int K) {
  __shared__ short As[128 * 32];
  __shared__ short Bs[128 * 32];
  int m0 = blockIdx.y * 128, n0 = blockIdx.x * 128;
  int tid = threadIdx.x;
  int wave = tid >> 6, lane = tid & 63;
  int wm = (wave >> 1) * 64, wn = (wave & 1) * 64;
  int quad = lane >> 4, l16 = lane & 15;
  f32x4 acc[4][4] = {};

  int ar = tid >> 2;
  int ac = (tid & 3) * 8;
  const short* Ag0 = A + (long)(m0 + ar) * K + ac;
  const short* Ag1 = A + (long)(m0 + 64 + ar) * K + ac;
  const short* Bg0 = Bt + (long)(n0 + ar) * K + ac;
  const short* Bg1 = Bt + (long)(n0 + 64 + ar) * K + ac;
  short* lA0 = As + tid * 8;
  short* lA1 = As + 64 * 32 + tid * 8;
  short* lB0 = Bs + tid * 8;
  short* lB1 = Bs + 64 * 32 + tid * 8;

  for (int k0 = 0; k0 < K; k0 += 32) {
    GLOAD_LDS16(Ag0 + k0, lA0);
    GLOAD_LDS16(Ag1 + k0, lA1);
    GLOAD_LDS16(Bg0 + k0, lB0);
    GLOAD_LDS16(Bg1 + k0, lB1);
    __syncthreads();

    short8 af[4], bf_[4];
#pragma unroll
    for (int i = 0; i < 4; ++i) af[i] = *(const short8*)(As + (wm + i * 16 + l16) * 32 + quad * 8);
#pragma unroll
    for (int j = 0; j < 4; ++j) bf_[j] = *(const short8*)(Bs + (wn + j * 16 + l16) * 32 + quad * 8);
#pragma unroll
    for (int i = 0; i < 4; ++i)
#pragma unroll
      for (int j = 0; j < 4; ++j)
        acc[i][j] = __builtin_amdgcn_mfma_f32_16x16x32_bf16(af[i], bf_[j], acc[i][j], 0, 0, 0);
    __syncthreads();
  }

#pragma unroll
  for (int i = 0; i < 4; ++i)
#pragma unroll
    for (int j = 0; j < 4; ++j)
#pragma unroll
      for (int r = 0; r < 4; ++r) {
        int row = m0 + wm + i * 16 + quad * 4 + r;
        int colx = n0 + wn + j * 16 + l16;
        C[(long)row * N + colx] = acc[i][j][r];
      }
}

// ---------------- beta / g projections (g stored in log space) ---------------
__global__ __launch_bounds__(256) void small_proj(const float* __restrict__ hidden,
                                                  const float* __restrict__ WbaT,
                                                  const float* __restrict__ dt_bias,
                                                  const float* __restrict__ A_log,
                                                  float* __restrict__ betaT,
                                                  float* __restrict__ gT) {
  __shared__ float red[256];
  int r = blockIdx.x;
  int tid = threadIdx.x;
  int h = tid & 31;
  int s = tid >> 5;
  const float4* hp = (const float4*)(hidden + (long)r * D_ + s * 256);
  const float4* wp = (const float4*)(WbaT + (long)h * D_ + s * 256);
  float acc = 0.f;
#pragma unroll 8
  for (int i = 0; i < 64; ++i) {
    float4 a = hp[i], w = wp[i];
    acc += a.x * w.x + a.y * w.y + a.z * w.z + a.w * w.w;
  }
  red[tid] = acc;
  __syncthreads();
  if (tid < 32) {
    float t = 0.f;
#pragma unroll
    for (int ss = 0; ss < 8; ++ss) t += red[ss * 32 + tid];
    if (tid < 16) {
      betaT[tid * BT_ + r] = 1.f / (1.f + __expf(-t));
    } else {
      int hh = tid - 16;
      float y = t + dt_bias[hh];
      float sp = fmaxf(y, 0.f) + log1pf(__expf(-fabsf(y)));
      gT[hh * BT_ + r] = -__expf(A_log[hh]) * sp;   // raw g (log decay)
    }
  }
}

// ---------------- depthwise causal conv (K=4) + SiLU ----------------
__global__ void conv_silu(const float* __restrict__ x, const float* __restrict__ w,
                          float* __restrict__ y) {
  int idx = blockIdx.x * 256 + threadIdx.x;
  int c = idx & (CONV_DIM_ - 1);
  int bt = idx >> 12;
  int t = bt & (T_ - 1);
  float4 wc = *(const float4*)(w + c * 4);
  const float* xp = x + (long)idx;
  float acc = wc.w * xp[0];
  if (t >= 1) acc += wc.z * xp[-CONV_DIM_];
  if (t >= 2) acc += wc.y * xp[-2 * CONV_DIM_];
  if (t >= 3) acc += wc.x * xp[-3 * CONV_DIM_];
  y[idx] = acc * (1.f / (1.f + __expf(-acc)));
}

// ---------------- q/k l2norm (+ q scale), bf16 out ----------------
__global__ __launch_bounds__(64) void qknorm(const float* __restrict__ qkv,
                                             short* __restrict__ qb, short* __restrict__ kb) {
  int bi = blockIdx.x;          // B*T*HK*2
  int which = bi & 1;
  int h = (bi >> 1) & 7;
  int bt = bi >> 4;
  int lane = threadIdx.x;
  const float* src = qkv + (long)bt * CONV_DIM_ + which * KEY_DIM_ + h * DK_;
  float2 v = *(const float2*)(src + lane * 2);
  float ss = v.x * v.x + v.y * v.y;
#pragma unroll
  for (int m = 32; m; m >>= 1) ss += __shfl_xor(ss, m, 64);
  float scale = rsqrtf(ss + 1e-6f);
  if (which == 0) scale *= 0.08838834764831845f;  // DK^-0.5
  short* dst = (which ? kb : qb) + ((long)bt * HK_ + h) * DK_;
  short2 o; o.x = f2bf(v.x * scale); o.y = f2bf(v.y * scale);
  ((short2*)dst)[lane] = o;
}

// per-column forward substitution: u_s = rhs_s - sum_{r<s} A[s][r] u_r
__device__ __forceinline__ void solve_col(const float* __restrict__ Al,
                                          float* __restrict__ Rc) {
  for (int s = 1; s < 64; ++s) {
    float u = Rc[s];
    const float* Ar = Al + s * 64;
    int r = 0;
    for (; r + 4 <= s; r += 4) {
      float4 a = *(const float4*)(Ar + r);
      float4 uu = *(const float4*)(Rc + r);
      u -= (a.x * uu.x + a.y * uu.y) + (a.z * uu.z + a.w * uu.w);
    }
    for (; r < s; ++r) u -= Ar[r] * Rc[r];
    Rc[s] = u;
  }
}

// ================= PHASE 1: per-chunk local quantities (parallel, 512 blocks)
// Outputs per chunk-instance ci = ((b*16+hv)*16 + c):
//   Pm  [64][64]  bf16 : tril-incl (QK^T (.) decay)
//   GQ  [64][128] bf16 : Gamma_t * q_t  (row-major)
//   KtT [128][64] bf16 : Ktilde^T, Ktilde_s = k_s * exp(G_C - G_s)
//   Wneg[64][128] bf16 : -T (beta Gamma (.) K)     (row-major)
//   Ut  [64][128] f32  : T (beta (.) V)            (row-major)
//   Gammac[ci]    f32  : exp(G_C)
__global__ __launch_bounds__(256) void chunk_phase1(
    const short* __restrict__ qbf, const short* __restrict__ kbf,
    const float* __restrict__ qkv, const float* __restrict__ gT,
    const float* __restrict__ bT,
    short* __restrict__ Pm, short* __restrict__ GQ, short* __restrict__ KtT,
    short* __restrict__ Wneg, float* __restrict__ Ut, float* __restrict__ Gammac) {
  __shared__ float Al[64 * 64];      // 16 KB
  __shared__ float RT[128 * 68];     // 34 KB, transposed RHS [col][r], pad 68
  __shared__ float Gs[64], Gam[64], Dd[64], Bet[64];

  int ci = blockIdx.x;
  int c = ci & 15, hv = (ci >> 4) & 15, b = ci >> 8;
  int hk = hv >> 1;
  int t0 = c * CL_;
  int tid = threadIdx.x;
  int wave = tid >> 6, lane = tid & 63, quad = lane >> 4, l16 = lane & 15;

  if (tid < 64) {
    float g = gT[(hv * B_ + b) * T_ + t0 + tid];
    float x = g;
#pragma unroll
    for (int off = 1; off < 64; off <<= 1) {
      float y = __shfl_up(x, off, 64);
      if (tid >= off) x += y;
    }
    Gs[tid] = x;
    Gam[tid] = __expf(x);
    float Gtot = __shfl(x, 63, 64);
    Dd[tid] = __expf(Gtot - x);
    Bet[tid] = bT[(hv * B_ + b) * T_ + t0 + tid];
    if (tid == 63) Gammac[ci] = __expf(x);
  }
  __syncthreads();

  const long kbase = ((long)(b * T_ + t0) * HK_ + hk) * DK_;   // in shorts
  const int kstride = HK_ * DK_;                               // 1024

  // ---- KK^T -> Al (mask s>r, scale beta_s * exp(G_s - G_r)) ----
  {
    f32x4 acc[4] = {};
#pragma unroll
    for (int kk = 0; kk < 4; ++kk) {
      short8 afr = *(const short8*)(kbf + kbase + (long)(16 * wave + l16) * kstride + kk * 32 + quad * 8);
#pragma unroll
      for (int j = 0; j < 4; ++j) {
        short8 bfr = *(const short8*)(kbf + kbase + (long)(16 * j + l16) * kstride + kk * 32 + quad * 8);
        acc[j] = __builtin_amdgcn_mfma_f32_16x16x32_bf16(afr, bfr, acc[j], 0, 0, 0);
      }
    }
#pragma unroll
    for (int j = 0; j < 4; ++j)
#pragma unroll
      for (int r = 0; r < 4; ++r) {
        int row = 16 * wave + quad * 4 + r, col = 16 * j + l16;
        float v = 0.f;
        if (row > col) v = Bet[row] * __expf(Gs[row] - Gs[col]) * acc[j][r];
        Al[row * 64 + col] = v;
      }
  }
  // ---- QK^T -> Pm (mask t>=s, scale exp(G_t - G_s)) ----
  {
    f32x4 acc[4] = {};
#pragma unroll
    for (int kk = 0; kk < 4; ++kk) {
      short8 afr = *(const short8*)(qbf + kbase + (long)(16 * wave + l16) * kstride + kk * 32 + quad * 8);
#pragma unroll
      for (int j = 0; j < 4; ++j) {
        short8 bfr = *(const short8*)(kbf + kbase + (long)(16 * j + l16) * kstride + kk * 32 + quad * 8);
        acc[j] = __builtin_amdgcn_mfma_f32_16x16x32_bf16(afr, bfr, acc[j], 0, 0, 0);
      }
    }
#pragma unroll
    for (int j = 0; j < 4; ++j)
#pragma unroll
      for (int r = 0; r < 4; ++r) {
        int row = 16 * wave + quad * 4 + r, col = 16 * j + l16;
        float v = 0.f;
        if (row >= col) v = __expf(Gs[row] - Gs[col]) * acc[j][r];
        Pm[(long)ci * 4096 + row * 64 + col] = f2bf(v);
      }
  }
  // ---- KtT, GQ ----
  {
    int d = tid >> 1, s0 = (tid & 1) * 32;
    for (int s = s0; s < s0 + 32; ++s) {
      float kv = bf2f(kbf[kbase + (long)s * kstride + d]);
      KtT[(long)ci * 8192 + d * 64 + s] = f2bf(kv * Dd[s]);
    }
    int s = tid >> 2, dq = (tid & 3) * 32;
    float gm = Gam[s];
    for (int i = 0; i < 32; ++i) {
      float qv = bf2f(qbf[kbase + (long)s * kstride + dq + i]);
      GQ[(long)ci * 8192 + s * 128 + dq + i] = f2bf(qv * gm);
    }
  }
  // ---- RHS1: RT[col][r] = beta_r * v[t0+r][col] ----
  const float* vbase = qkv + (long)(b * T_ + t0) * CONV_DIM_ + 2 * KEY_DIM_ + hv * DV_;
  for (int idx = tid; idx < 8192; idx += 256) {
    int r = idx >> 7, col = idx & 127;
    RT[col * 68 + r] = Bet[r] * vbase[(long)r * CONV_DIM_ + col];
  }
  __syncthreads();
  if (tid < 128) solve_col(Al, RT + tid * 68);
  __syncthreads();
  for (int idx = tid; idx < 8192; idx += 256) {
    int s = idx >> 7, col = idx & 127;
    Ut[(long)ci * 8192 + idx] = RT[col * 68 + s];
  }
  __syncthreads();
  // ---- RHS2: RT[col][r] = beta_r * Gamma_r * k[t0+r][col] ----
  for (int idx = tid; idx < 8192; idx += 256) {
    int r = idx >> 7, col = idx & 127;
    float kv = bf2f(kbf[kbase + (long)r * kstride + col]);
    RT[col * 68 + r] = Bet[r] * Gam[r] * kv;
  }
  __syncthreads();
  if (tid < 128) solve_col(Al, RT + tid * 68);
  __syncthreads();
  for (int idx = tid; idx < 8192; idx += 256) {
    int s = idx >> 7, col = idx & 127;
    Wneg[(long)ci * 8192 + idx] = f2bf(-RT[col * 68 + s]);
  }
}

// ================= PHASE 2: state recurrence over chunks (32 blocks) =========
// S register-resident (C-frag layout). Per chunk: store Sc^T, U = Ut + Wneg*S,
// store U^T, S = gamma_c*S + Ktilde^T * U.
__global__ __launch_bounds__(256) void chunk_phase2(
    const short* __restrict__ Wneg, const float* __restrict__ Ut,
    const short* __restrict__ KtT, const float* __restrict__ Gammac,
    short* __restrict__ UTg, short* __restrict__ ScTg) {
  __shared__ short SLT[128 * 136];   // S^T [n][m], pad 136
  __shared__ short ULT[128 * 72];    // U^T [n][s], pad 72
  int bi = blockIdx.x;               // b*16+hv
  int tid = threadIdx.x, wave = tid >> 6, lane = tid & 63, quad = lane >> 4, l16 = lane & 15;
  f32x4 S[2][8] = {};

  for (int ch = 0; ch < NCH_; ++ch) {
    long ci = (long)bi * NCH_ + ch;
    // S -> SLT (lds) and ScTg (global), bf16 transposed
#pragma unroll
    for (int i = 0; i < 2; ++i)
#pragma unroll
      for (int j = 0; j < 8; ++j) {
        int m0 = 32 * wave + 16 * i + quad * 4;
        int n = 16 * j + l16;
        short4 p;
        p.x = f2bf(S[i][j][0]); p.y = f2bf(S[i][j][1]);
        p.z = f2bf(S[i][j][2]); p.w = f2bf(S[i][j][3]);
        *(short4*)(SLT + n * 136 + m0) = p;
        *(short4*)(ScTg + ci * 16384 + n * 128 + m0) = p;
      }
    __syncthreads();
    // U = Ut + Wneg * S   (wave w: U rows 16w..16w+15)
    f32x4 Ua[8];
#pragma unroll
    for (int j = 0; j < 8; ++j) {
      const float* up = Ut + ci * 8192 + (16 * wave + quad * 4) * 128 + 16 * j + l16;
#pragma unroll
      for (int r = 0; r < 4; ++r) Ua[j][r] = up[r * 128];
    }
#pragma unroll
    for (int kk = 0; kk < 4; ++kk) {
      short8 af = *(const short8*)(Wneg + ci * 8192 + (16 * wave + l16) * 128 + kk * 32 + quad * 8);
#pragma unroll
      for (int j = 0; j < 8; ++j) {
        short8 bfv = *(const short8*)(SLT + (16 * j + l16) * 136 + kk * 32 + quad * 8);
        Ua[j] = __builtin_amdgcn_mfma_f32_16x16x32_bf16(af, bfv, Ua[j], 0, 0, 0);
      }
    }
#pragma unroll
    for (int j = 0; j < 8; ++j) {
      int n = 16 * j + l16, s0 = 16 * wave + quad * 4;
      short4 p;
      p.x = f2bf(Ua[j][0]); p.y = f2bf(Ua[j][1]);
      p.z = f2bf(Ua[j][2]); p.w = f2bf(Ua[j][3]);
      *(short4*)(ULT + n * 72 + s0) = p;
      *(short4*)(UTg + ci * 8192 + n * 64 + s0) = p;
    }
    __syncthreads();
    // S = gc*S + Ktilde^T U
    float gc = Gammac[ci];
#pragma unroll
    for (int i = 0; i < 2; ++i)
#pragma unroll
      for (int j = 0; j < 8; ++j)
#pragma unroll
        for (int r = 0; r < 4; ++r) S[i][j][r] *= gc;
#pragma unroll
    for (int kk = 0; kk < 2; ++kk)
#pragma unroll
      for (int i = 0; i < 2; ++i) {
        short8 af = *(const short8*)(KtT + ci * 8192 + (32 * wave + 16 * i + l16) * 64 + kk * 32 + quad * 8);
#pragma unroll
        for (int j = 0; j < 8; ++j) {
          short8 bfv = *(const short8*)(ULT + (16 * j + l16) * 72 + kk * 32 + quad * 8);
          S[i][j] = __builtin_amdgcn_mfma_f32_16x16x32_bf16(af, bfv, S[i][j], 0, 0, 0);
        }
      }
    __syncthreads();
  }
}

// ================= PHASE 3: outputs (parallel, 512 blocks) ===================
// O = GQ * Sc + Pm * U
__global__ __launch_bounds__(256) void chunk_phase3(
    const short* __restrict__ GQ, const short* __restrict__ ScTg,
    const short* __restrict__ Pm, const short* __restrict__ UTg,
    float* __restrict__ obuf) {
  int ci = blockIdx.x;
  int c = ci & 15, hv = (ci >> 4) & 15, b = ci >> 8;
  int t0 = c * CL_;
  int tid = threadIdx.x, wave = tid >> 6, lane = tid & 63, quad = lane >> 4, l16 = lane & 15;
  f32x4 acc[8] = {};
#pragma unroll
  for (int kk = 0; kk < 4; ++kk) {
    short8 af = *(const short8*)(GQ + (long)ci * 8192 + (16 * wave + l16) * 128 + kk * 32 + quad * 8);
#pragma unroll
    for (int j = 0; j < 8; ++j) {
      short8 bfv = *(const short8*)(ScTg + (long)ci * 16384 + (16 * j + l16) * 128 + kk * 32 + quad * 8);
      acc[j] = __builtin_amdgcn_mfma_f32_16x16x32_bf16(af, bfv, acc[j], 0, 0, 0);
    }
  }
#pragma unroll
  for (int kk = 0; kk < 2; ++kk) {
    short8 af = *(const short8*)(Pm + (long)ci * 4096 + (16 * wave + l16) * 64 + kk * 32 + quad * 8);
#pragma unroll
    for (int j = 0; j < 8; ++j) {
      short8 bfv = *(const short8*)(UTg + (long)ci * 8192 + (16 * j + l16) * 64 + kk * 32 + quad * 8);
      acc[j] = __builtin_amdgcn_mfma_f32_16x16x32_bf16(af, bfv, acc[j], 0, 0, 0);
    }
  }
#pragma unroll
  for (int j = 0; j < 8; ++j)
#pragma unroll
    for (int r = 0; r < 4; ++r) {
      int t = t0 + 16 * wave + quad * 4 + r;
      int n = 16 * j + l16;
      obuf[((long)(b * T_ + t) * HV_ + hv) * DV_ + n] = acc[j][r];
    }
}

// ---------------- gated RMSNorm * silu(z), cast to bf16 ----------------
__global__ __launch_bounds__(64) void rms_gate(const float* __restrict__ obuf,
                                               const float* __restrict__ zbuf,
                                               const float* __restrict__ nw,
                                               short* __restrict__ obf) {
  int bi = blockIdx.x;
  int hv = bi & 15;
  int bt = bi >> 4;
  int lane = threadIdx.x;
  const float* o = obuf + ((long)bt * HV_ + hv) * DV_;
  float2 ov = *(const float2*)(o + lane * 2);
  float ss = ov.x * ov.x + ov.y * ov.y;
#pragma unroll
  for (int m = 32; m; m >>= 1) ss += __shfl_xor(ss, m, 64);
  float scale = rsqrtf(ss * (1.f / 128.f) + 1e-6f);
  float2 wv = *(const float2*)(nw + lane * 2);
  const float* z = zbuf + (long)bt * VALUE_DIM_ + hv * DV_;
  float2 zv = *(const float2*)(z + lane * 2);
  float s0 = zv.x * (1.f / (1.f + __expf(-zv.x)));
  float s1 = zv.y * (1.f / (1.f + __expf(-zv.y)));
  short2 r;
  r.x = f2bf(ov.x * scale * wv.x * s0);
  r.y = f2bf(ov.y * scale * wv.y * s1);
  ((short2*)(obf + ((long)bt * VALUE_DIM_ + hv * DV_)))[lane] = r;
}

// ---------------- launcher ----------------
extern "C" void kernel_launch(void* const* d_in, const int* in_sizes, int n_in,
                              void* d_out, int out_size, void* d_ws, size_t ws_size,
                              hipStream_t stream) {
  const float* hidden  = (const float*)d_in[0];
  const float* W_qkv   = (const float*)d_in[1];
  const float* W_z     = (const float*)d_in[2];
  const float* W_b     = (const float*)d_in[3];
  const float* W_a     = (const float*)d_in[4];
  const float* conv_w  = (const float*)d_in[5];
  const float* dt_bias = (const float*)d_in[6];
  const float* A_log   = (const float*)d_in[7];
  const float* norm_w  = (const float*)d_in[8];
  const float* W_out   = (const float*)d_in[9];
  float* out = (float*)d_out;

  char* ws = (char*)d_ws;
  size_t off = 0;
  auto alloc = [&](size_t bytes) {
    void* p = ws + off;
    off += (bytes + 255) & ~(size_t)255;
    return p;
  };
  short* hidden_bf = (short*)alloc((size_t)BT_ * D_ * 2);           // 8 MB
  short* WqkvT     = (short*)alloc((size_t)CONV_DIM_ * D_ * 2);     // 16 MB
  short* WzT       = (short*)alloc((size_t)VALUE_DIM_ * D_ * 2);    // 8 MB
  short* WoutT     = (short*)alloc((size_t)D_ * VALUE_DIM_ * 2);    // 8 MB
  float* mixed     = (float*)alloc((size_t)BT_ * CONV_DIM_ * 4);    // 32 MB
  float* qkv       = (float*)alloc((size_t)BT_ * CONV_DIM_ * 4);    // 32 MB
  float* zbuf      = (float*)alloc((size_t)BT_ * VALUE_DIM_ * 4);   // 16 MB
  short* qbf       = (short*)alloc((size_t)BT_ * KEY_DIM_ * 2);     // 4 MB
  short* kbf       = (short*)alloc((size_t)BT_ * KEY_DIM_ * 2);     // 4 MB
  float* betab     = (float*)alloc((size_t)BT_ * HV_ * 4);
  float* gb        = (float*)alloc((size_t)BT_ * HV_ * 4);
  float* WbaT      = (float*)alloc((size_t)32 * D_ * 4);            // 256 KB
  short* Wneg      = (short*)alloc((size_t)512 * 8192 * 2);         // 8 MB
  float* Ut32      = (float*)alloc((size_t)512 * 8192 * 4);         // 16 MB
  short* KtT       = (short*)alloc((size_t)512 * 8192 * 2);         // 8 MB
  short* UTg       = (short*)alloc((size_t)512 * 8192 * 2);         // 8 MB
  short* ScTg      = (short*)alloc((size_t)512 * 16384 * 2);        // 16 MB
  float* Gammac    = (float*)alloc((size_t)512 * 4);
  // aliases into mixed (dead after conv_silu):
  float* obuf = mixed;                                 // 16 MB (phase3 out)
  short* Pm   = (short*)(mixed + (size_t)BT_ * VALUE_DIM_);         // 4 MB
  short* GQ   = Pm + (size_t)512 * 4096;                            // 8 MB
  short* obf  = hidden_bf;   // dead after gemm(z)

  dim3 tb32(32, 8);
  cast_plain<<<(BT_ * D_ / 4 + 255) / 256, 256, 0, stream>>>(hidden, hidden_bf, BT_ * D_ / 4);
  transpose_cast<<<dim3(CONV_DIM_ / 32, D_ / 32), tb32, 0, stream>>>(W_qkv, WqkvT, D_, CONV_DIM_);
  transpose_cast<<<dim3(VALUE_DIM_ / 32, D_ / 32), tb32, 0, stream>>>(W_z, WzT, D_, VALUE_DIM_);
  transpose_cast<<<dim3(D_ / 32, VALUE_DIM_ / 32), tb32, 0, stream>>>(W_out, WoutT, VALUE_DIM_, D_);
  transpose_ba<<<32 * D_ / 256, 256, 0, stream>>>(W_b, W_a, WbaT);

  gemm128<<<dim3(CONV_DIM_ / 128, BT_ / 128), 256, 0, stream>>>(hidden_bf, WqkvT, mixed, BT_, CONV_DIM_, D_);
  gemm128<<<dim3(VALUE_DIM_ / 128, BT_ / 128), 256, 0, stream>>>(hidden_bf, WzT, zbuf, BT_, VALUE_DIM_, D_);
  small_proj<<<BT_, 256, 0, stream>>>(hidden, WbaT, dt_bias, A_log, betab, gb);
  conv_silu<<<BT_ * CONV_DIM_ / 256, 256, 0, stream>>>(mixed, conv_w, qkv);
  qknorm<<<BT_ * HK_ * 2, 64, 0, stream>>>(qkv, qbf, kbf);

  chunk_phase1<<<512, 256, 0, stream>>>(qbf, kbf, qkv, gb, betab, Pm, GQ, KtT, Wneg, Ut32, Gammac);
  chunk_phase2<<<32, 256, 0, stream>>>(Wneg, Ut32, KtT, Gammac, UTg, ScTg);
  chunk_phase3<<<512, 256, 0, stream>>>(GQ, ScTg, Pm, UTg, obuf);

  rms_gate<<<BT_ * HV_, 64, 0, stream>>>(obuf, zbuf, norm_w, obf);
  gemm128<<<dim3(D_ / 128, BT_ / 128), 256, 0, stream>>>(obf, WoutT, out, BT_, D_, VALUE_DIM_);
}

// Round 5
// 527.279 us; speedup vs baseline: 1.3580x; 1.1567x over previous
//
#include <hip/hip_runtime.h>
#include <hip/hip_bf16.h>

// GatedDeltaNet: B=2, T=1024, D=2048, HK=8, HV=16, DK=DV=128, KW=4
#define B_ 2
#define T_ 1024
#define D_ 2048
#define HK_ 8
#define HV_ 16
#define DK_ 128
#define DV_ 128
#define KEY_DIM_ 1024
#define VALUE_DIM_ 2048
#define CONV_DIM_ 4096
#define BT_ 2048   // B*T
#define NCH_ 16    // chunks per sequence (T/64)
#define CL_ 64     // chunk length

typedef __attribute__((ext_vector_type(8))) short short8;
typedef __attribute__((ext_vector_type(4))) float f32x4;

__device__ __forceinline__ short f2bf(float x) {
  __hip_bfloat16 h = __float2bfloat16(x);
  return *reinterpret_cast<short*>(&h);
}
__device__ __forceinline__ float bf2f(short u) {
  unsigned int x = ((unsigned int)(unsigned short)u) << 16;
  return __int_as_float(x);
}

#define GLOAD_LDS16(g, l)                                             \
  __builtin_amdgcn_global_load_lds(                                   \
      (const __attribute__((address_space(1))) void*)(g),             \
      (__attribute__((address_space(3))) void*)(l), 16, 0, 0)

// ---------------- cast f32 -> bf16 ----------------
__global__ void cast_plain(const float* __restrict__ in, short* __restrict__ out, int n4) {
  int i = blockIdx.x * blockDim.x + threadIdx.x;
  if (i < n4) {
    float4 v = ((const float4*)in)[i];
    short4 o;
    o.x = f2bf(v.x); o.y = f2bf(v.y); o.z = f2bf(v.z); o.w = f2bf(v.w);
    ((short4*)out)[i] = o;
  }
}

// ---------------- transpose + cast: W[R,C] f32 -> WT[C,R] bf16 ----------------
__global__ void transpose_cast(const float* __restrict__ W, short* __restrict__ WT, int R, int C) {
  __shared__ float tile[32][33];
  int tx = threadIdx.x, ty = threadIdx.y;
  int x = blockIdx.x * 32 + tx;
#pragma unroll
  for (int j = 0; j < 4; ++j) {
    int r = blockIdx.y * 32 + ty + j * 8;
    tile[ty + j * 8][tx] = W[(long)r * C + x];
  }
  __syncthreads();
  int ro = blockIdx.y * 32 + tx;
#pragma unroll
  for (int j = 0; j < 4; ++j) {
    int co = blockIdx.x * 32 + ty + j * 8;
    WT[(long)co * R + ro] = f2bf(tile[tx][ty + j * 8]);
  }
}

// ---------------- W_b|W_a -> WbaT[32][D] ----------------
__global__ void transpose_ba(const float* __restrict__ Wb, const float* __restrict__ Wa,
                             float* __restrict__ WbaT) {
  int i = blockIdx.x * 256 + threadIdx.x;
  int c = i & 31, r = i >> 5;
  float v = (c < 16) ? Wb[r * 16 + c] : Wa[r * 16 + (c - 16)];
  WbaT[c * D_ + r] = v;
}

// ---------------- bf16 MFMA GEMM (m97-style) ----------------
__global__ __launch_bounds__(256) void gemm128(const short* __restrict__ A,
                                               const short* __restrict__ Bt,
                                               float* __restrict__ C,
                                               int M, int N, int K) {
  __shared__ short As[128 * 32];
  __shared__ short Bs[128 * 32];
  int m0 = blockIdx.y * 128, n0 = blockIdx.x * 128;
  int tid = threadIdx.x;
  int wave = tid >> 6, lane = tid & 63;
  int wm = (wave >> 1) * 64, wn = (wave & 1) * 64;
  int quad = lane >> 4, l16 = lane & 15;
  f32x4 acc[4][4] = {};

  int ar = tid >> 2;
  int ac = (tid & 3) * 8;
  const short* Ag0 = A + (long)(m0 + ar) * K + ac;
  const short* Ag1 = A + (long)(m0 + 64 + ar) * K + ac;
  const short* Bg0 = Bt + (long)(n0 + ar) * K + ac;
  const short* Bg1 = Bt + (long)(n0 + 64 + ar) * K + ac;
  short* lA0 = As + tid * 8;
  short* lA1 = As + 64 * 32 + tid * 8;
  short* lB0 = Bs + tid * 8;
  short* lB1 = Bs + 64 * 32 + tid * 8;

  for (int k0 = 0; k0 < K; k0 += 32) {
    GLOAD_LDS16(Ag0 + k0, lA0);
    GLOAD_LDS16(Ag1 + k0, lA1);
    GLOAD_LDS16(Bg0 + k0, lB0);
    GLOAD_LDS16(Bg1 + k0, lB1);
    __syncthreads();

    short8 af[4], bf_[4];
#pragma unroll
    for (int i = 0; i < 4; ++i) af[i] = *(const short8*)(As + (wm + i * 16 + l16) * 32 + quad * 8);
#pragma unroll
    for (int j = 0; j < 4; ++j) bf_[j] = *(const short8*)(Bs + (wn + j * 16 + l16) * 32 + quad * 8);
#pragma unroll
    for (int i = 0; i < 4; ++i)
#pragma unroll
      for (int j = 0; j < 4; ++j)
        acc[i][j] = __builtin_amdgcn_mfma_f32_16x16x32_bf16(af[i], bf_[j], acc[i][j], 0, 0, 0);
    __syncthreads();
  }

#pragma unroll
  for (int i = 0; i < 4; ++i)
#pragma unroll
    for (int j = 0; j < 4; ++j)
#pragma unroll
      for (int r = 0; r < 4; ++r) {
        int row = m0 + wm + i * 16 + quad * 4 + r;
        int colx = n0 + wn + j * 16 + l16;
        C[(long)row * N + colx] = acc[i][j][r];
      }
}

// ---------------- beta / g projections (g stored in log space) ---------------
__global__ __launch_bounds__(256) void small_proj(const float* __restrict__ hidden,
                                                  const float* __restrict__ WbaT,
                                                  const float* __restrict__ dt_bias,
                                                  const float* __restrict__ A_log,
                                                  float* __restrict__ betaT,
                                                  float* __restrict__ gT) {
  __shared__ float red[256];
  int r = blockIdx.x;
  int tid = threadIdx.x;
  int h = tid & 31;
  int s = tid >> 5;
  const float4* hp = (const float4*)(hidden + (long)r * D_ + s * 256);
  const float4* wp = (const float4*)(WbaT + (long)h * D_ + s * 256);
  float acc = 0.f;
#pragma unroll 8
  for (int i = 0; i < 64; ++i) {
    float4 a = hp[i], w = wp[i];
    acc += a.x * w.x + a.y * w.y + a.z * w.z + a.w * w.w;
  }
  red[tid] = acc;
  __syncthreads();
  if (tid < 32) {
    float t = 0.f;
#pragma unroll
    for (int ss = 0; ss < 8; ++ss) t += red[ss * 32 + tid];
    if (tid < 16) {
      betaT[tid * BT_ + r] = 1.f / (1.f + __expf(-t));
    } else {
      int hh = tid - 16;
      float y = t + dt_bias[hh];
      float sp = fmaxf(y, 0.f) + log1pf(__expf(-fabsf(y)));
      gT[hh * BT_ + r] = -__expf(A_log[hh]) * sp;   // raw g (log decay)
    }
  }
}

// ---------------- depthwise causal conv (K=4) + SiLU ----------------
__global__ void conv_silu(const float* __restrict__ x, const float* __restrict__ w,
                          float* __restrict__ y) {
  int idx = blockIdx.x * 256 + threadIdx.x;
  int c = idx & (CONV_DIM_ - 1);
  int bt = idx >> 12;
  int t = bt & (T_ - 1);
  float4 wc = *(const float4*)(w + c * 4);
  const float* xp = x + (long)idx;
  float acc = wc.w * xp[0];
  if (t >= 1) acc += wc.z * xp[-CONV_DIM_];
  if (t >= 2) acc += wc.y * xp[-2 * CONV_DIM_];
  if (t >= 3) acc += wc.x * xp[-3 * CONV_DIM_];
  y[idx] = acc * (1.f / (1.f + __expf(-acc)));
}

// ---------------- q/k l2norm (+ q scale), bf16 out ----------------
__global__ __launch_bounds__(64) void qknorm(const float* __restrict__ qkv,
                                             short* __restrict__ qb, short* __restrict__ kb) {
  int bi = blockIdx.x;          // B*T*HK*2
  int which = bi & 1;
  int h = (bi >> 1) & 7;
  int bt = bi >> 4;
  int lane = threadIdx.x;
  const float* src = qkv + (long)bt * CONV_DIM_ + which * KEY_DIM_ + h * DK_;
  float2 v = *(const float2*)(src + lane * 2);
  float ss = v.x * v.x + v.y * v.y;
#pragma unroll
  for (int m = 32; m; m >>= 1) ss += __shfl_xor(ss, m, 64);
  float scale = rsqrtf(ss + 1e-6f);
  if (which == 0) scale *= 0.08838834764831845f;  // DK^-0.5
  short* dst = (which ? kb : qb) + ((long)bt * HK_ + h) * DK_;
  short2 o; o.x = f2bf(v.x * scale); o.y = f2bf(v.y * scale);
  ((short2*)dst)[lane] = o;
}

// ================= PHASE 1: per-chunk local quantities (parallel, 512 blocks)
// Outputs per chunk-instance ci = ((b*16+hv)*16 + c):
//   Pm  [64][64]  bf16 : tril-incl (QK^T (.) decay)
//   GQ  [64][128] bf16 : Gamma_t * q_t  (row-major)
//   KtT [128][64] bf16 : Ktilde^T, Ktilde_s = k_s * exp(G_C - G_s)
//   Wneg[64][128] bf16 : -T (beta Gamma (.) K)     (row-major)
//   Ut  [64][128] f32  : T (beta (.) V)            (row-major)
//   Gammac[ci]    f32  : exp(G_C)
// Triangular solve: register-resident per-column forward substitution, 256
// columns (V-half + betaGammaK-half) solved simultaneously; A rows broadcast
// from LDS (conflict-free).
__global__ __launch_bounds__(256, 2) void chunk_phase1(
    const short* __restrict__ qbf, const short* __restrict__ kbf,
    const float* __restrict__ qkv, const float* __restrict__ gT,
    const float* __restrict__ bT,
    short* __restrict__ Pm, short* __restrict__ GQ, short* __restrict__ KtT,
    short* __restrict__ Wneg, float* __restrict__ Ut, float* __restrict__ Gammac) {
  __shared__ float Al[64 * 64];      // 16 KB
  __shared__ float Gs[64], Gam[64], Dd[64], Bet[64], BG[64];

  int ci = blockIdx.x;
  int c = ci & 15, hv = (ci >> 4) & 15, b = ci >> 8;
  int hk = hv >> 1;
  int t0 = c * CL_;
  int tid = threadIdx.x;
  int wave = tid >> 6, lane = tid & 63, quad = lane >> 4, l16 = lane & 15;

  if (tid < 64) {
    float g = gT[(hv * B_ + b) * T_ + t0 + tid];
    float x = g;
#pragma unroll
    for (int off = 1; off < 64; off <<= 1) {
      float y = __shfl_up(x, off, 64);
      if (tid >= off) x += y;
    }
    Gs[tid] = x;
    float gm = __expf(x);
    Gam[tid] = gm;
    float Gtot = __shfl(x, 63, 64);
    Dd[tid] = __expf(Gtot - x);
    float bb = bT[(hv * B_ + b) * T_ + t0 + tid];
    Bet[tid] = bb;
    BG[tid] = bb * gm;
    if (tid == 63) Gammac[ci] = __expf(x);
  }
  __syncthreads();

  const long kbase = ((long)(b * T_ + t0) * HK_ + hk) * DK_;   // in shorts
  const int kstride = HK_ * DK_;                               // 1024

  // ---- RHS columns into registers (coalesced: lane-consecutive cols) ----
  int half = tid >> 7;        // 0 = V-columns, 1 = betaGammaK-columns
  int col = tid & 127;
  float u[64];
  {
    const float* vcol = qkv + (long)(b * T_ + t0) * CONV_DIM_ + 2 * KEY_DIM_ + hv * DV_ + col;
    const short* kcol = kbf + kbase + col;
    if (half == 0) {
#pragma unroll
      for (int r = 0; r < 64; ++r) u[r] = vcol[(long)r * CONV_DIM_];
    } else {
#pragma unroll
      for (int r = 0; r < 64; ++r) u[r] = bf2f(kcol[(long)r * kstride]);
    }
  }

  // ---- KK^T -> Al (mask s>r, scale beta_s * exp(G_s - G_r)) ----
  {
    f32x4 acc[4] = {};
#pragma unroll
    for (int kk = 0; kk < 4; ++kk) {
      short8 afr = *(const short8*)(kbf + kbase + (long)(16 * wave + l16) * kstride + kk * 32 + quad * 8);
#pragma unroll
      for (int j = 0; j < 4; ++j) {
        short8 bfr = *(const short8*)(kbf + kbase + (long)(16 * j + l16) * kstride + kk * 32 + quad * 8);
        acc[j] = __builtin_amdgcn_mfma_f32_16x16x32_bf16(afr, bfr, acc[j], 0, 0, 0);
      }
    }
#pragma unroll
    for (int j = 0; j < 4; ++j)
#pragma unroll
      for (int r = 0; r < 4; ++r) {
        int row = 16 * wave + quad * 4 + r, colx = 16 * j + l16;
        float v = 0.f;
        if (row > colx) v = Bet[row] * __expf(Gs[row] - Gs[colx]) * acc[j][r];
        Al[row * 64 + colx] = v;
      }
  }
  // ---- QK^T -> Pm (mask t>=s, scale exp(G_t - G_s)) ----
  {
    f32x4 acc[4] = {};
#pragma unroll
    for (int kk = 0; kk < 4; ++kk) {
      short8 afr = *(const short8*)(qbf + kbase + (long)(16 * wave + l16) * kstride + kk * 32 + quad * 8);
#pragma unroll
      for (int j = 0; j < 4; ++j) {
        short8 bfr = *(const short8*)(kbf + kbase + (long)(16 * j + l16) * kstride + kk * 32 + quad * 8);
        acc[j] = __builtin_amdgcn_mfma_f32_16x16x32_bf16(afr, bfr, acc[j], 0, 0, 0);
      }
    }
#pragma unroll
    for (int j = 0; j < 4; ++j)
#pragma unroll
      for (int r = 0; r < 4; ++r) {
        int row = 16 * wave + quad * 4 + r, colx = 16 * j + l16;
        float v = 0.f;
        if (row >= colx) v = __expf(Gs[row] - Gs[colx]) * acc[j][r];
        Pm[(long)ci * 4096 + row * 64 + colx] = f2bf(v);
      }
  }
  // ---- GQ[s][d] = Gam[s]*q[s][d] (coalesced short2 writes) ----
  for (int s = wave; s < 64; s += 4) {
    float gm = Gam[s];
    short2 qv = *(const short2*)(qbf + kbase + (long)s * kstride + lane * 2);
    short2 o;
    o.x = f2bf(bf2f(qv.x) * gm);
    o.y = f2bf(bf2f(qv.y) * gm);
    *(short2*)(GQ + (long)ci * 8192 + s * 128 + lane * 2) = o;
  }
  // ---- KtT[d][s] = k[s][d]*Dd[s] (coalesced 2B writes; scattered reads hit L1) ----
  for (int d = wave; d < 128; d += 4) {
    float kv = bf2f(kbf[kbase + (long)lane * kstride + d]);
    KtT[(long)ci * 8192 + d * 64 + lane] = f2bf(kv * Dd[lane]);
  }
  __syncthreads();   // Al complete

  // ---- scale RHS, register-resident forward substitution ----
  if (half == 0) {
#pragma unroll
    for (int r = 0; r < 64; ++r) u[r] *= Bet[r];
  } else {
#pragma unroll
    for (int r = 0; r < 64; ++r) u[r] *= BG[r];
  }
#pragma unroll
  for (int s = 1; s < 64; ++s) {
    const float* Ar = Al + s * 64;
    float acc = 0.f;
#pragma unroll
    for (int r4 = 0; r4 + 4 <= s; r4 += 4) {
      float4 a = *(const float4*)(Ar + r4);
      acc += (a.x * u[r4] + a.y * u[r4 + 1]) + (a.z * u[r4 + 2] + a.w * u[r4 + 3]);
    }
#pragma unroll
    for (int r = (s / 4) * 4; r < s; ++r) acc += Ar[r] * u[r];
    u[s] -= acc;
  }
  // ---- write out (coalesced) ----
  if (half == 0) {
    float* up = Ut + (long)ci * 8192 + col;
#pragma unroll
    for (int s = 0; s < 64; ++s) up[s * 128] = u[s];
  } else {
    short* wp = Wneg + (long)ci * 8192 + col;
#pragma unroll
    for (int s = 0; s < 64; ++s) wp[s * 128] = f2bf(-u[s]);
  }
}

// ================= PHASE 2: state recurrence over chunks (64 blocks) =========
// Column-separable: block = (b*16+hv, col-half). S half register-resident.
__global__ __launch_bounds__(256) void chunk_phase2(
    const short* __restrict__ Wneg, const float* __restrict__ Ut,
    const short* __restrict__ KtT, const float* __restrict__ Gammac,
    short* __restrict__ UTg, short* __restrict__ ScTg) {
  __shared__ short SLT[64 * 136];   // S^T half [n 64][m 128 pad 136], 17 KB
  __shared__ short ULT[64 * 72];    // U^T half [n 64][s 64 pad 72], 9 KB
  int bi = blockIdx.x >> 1;          // b*16+hv
  int n0 = (blockIdx.x & 1) * 64;    // col-half base
  int tid = threadIdx.x, wave = tid >> 6, lane = tid & 63, quad = lane >> 4, l16 = lane & 15;
  f32x4 S[2][4] = {};   // rows 32*wave+16i+quad*4, cols n0+16j+l16

  for (int ch = 0; ch < NCH_; ++ch) {
    long ci = (long)bi * NCH_ + ch;
    // S -> SLT (lds) and ScTg (global), bf16 transposed
#pragma unroll
    for (int i = 0; i < 2; ++i)
#pragma unroll
      for (int j = 0; j < 4; ++j) {
        int m0 = 32 * wave + 16 * i + quad * 4;
        int n = 16 * j + l16;
        short4 p;
        p.x = f2bf(S[i][j][0]); p.y = f2bf(S[i][j][1]);
        p.z = f2bf(S[i][j][2]); p.w = f2bf(S[i][j][3]);
        *(short4*)(SLT + n * 136 + m0) = p;
        *(short4*)(ScTg + ci * 16384 + (n0 + n) * 128 + m0) = p;
      }
    __syncthreads();
    // U = Ut + Wneg * S   (wave w: U rows 16w..16w+15, cols n0..n0+63)
    f32x4 Ua[4];
#pragma unroll
    for (int j = 0; j < 4; ++j) {
      const float* up = Ut + ci * 8192 + (16 * wave + quad * 4) * 128 + n0 + 16 * j + l16;
#pragma unroll
      for (int r = 0; r < 4; ++r) Ua[j][r] = up[r * 128];
    }
#pragma unroll
    for (int kk = 0; kk < 4; ++kk) {
      short8 af = *(const short8*)(Wneg + ci * 8192 + (16 * wave + l16) * 128 + kk * 32 + quad * 8);
#pragma unroll
      for (int j = 0; j < 4; ++j) {
        short8 bfv = *(const short8*)(SLT + (16 * j + l16) * 136 + kk * 32 + quad * 8);
        Ua[j] = __builtin_amdgcn_mfma_f32_16x16x32_bf16(af, bfv, Ua[j], 0, 0, 0);
      }
    }
#pragma unroll
    for (int j = 0; j < 4; ++j) {
      int n = 16 * j + l16, s0q = 16 * wave + quad * 4;
      short4 p;
      p.x = f2bf(Ua[j][0]); p.y = f2bf(Ua[j][1]);
      p.z = f2bf(Ua[j][2]); p.w = f2bf(Ua[j][3]);
      *(short4*)(ULT + n * 72 + s0q) = p;
      *(short4*)(UTg + ci * 8192 + (n0 + n) * 64 + s0q) = p;
    }
    __syncthreads();
    // S = gc*S + Ktilde^T U
    float gc = Gammac[ci];
#pragma unroll
    for (int i = 0; i < 2; ++i)
#pragma unroll
      for (int j = 0; j < 4; ++j)
#pragma unroll
        for (int r = 0; r < 4; ++r) S[i][j][r] *= gc;
#pragma unroll
    for (int kk = 0; kk < 2; ++kk)
#pragma unroll
      for (int i = 0; i < 2; ++i) {
        short8 af = *(const short8*)(KtT + ci * 8192 + (32 * wave + 16 * i + l16) * 64 + kk * 32 + quad * 8);
#pragma unroll
        for (int j = 0; j < 4; ++j) {
          short8 bfv = *(const short8*)(ULT + (16 * j + l16) * 72 + kk * 32 + quad * 8);
          S[i][j] = __builtin_amdgcn_mfma_f32_16x16x32_bf16(af, bfv, S[i][j], 0, 0, 0);
        }
      }
    __syncthreads();
  }
}

// ================= PHASE 3: outputs (parallel, 512 blocks) ===================
// O = GQ * Sc + Pm * U
__global__ __launch_bounds__(256) void chunk_phase3(
    const short* __restrict__ GQ, const short* __restrict__ ScTg,
    const short* __restrict__ Pm, const short* __restrict__ UTg,
    float* __restrict__ obuf) {
  int ci = blockIdx.x;
  int c = ci & 15, hv = (ci >> 4) & 15, b = ci >> 8;
  int t0 = c * CL_;
  int tid = threadIdx.x, wave = tid >> 6, lane = tid & 63, quad = lane >> 4, l16 = lane & 15;
  f32x4 acc[8] = {};
#pragma unroll
  for (int kk = 0; kk < 4; ++kk) {
    short8 af = *(const short8*)(GQ + (long)ci * 8192 + (16 * wave + l16) * 128 + kk * 32 + quad * 8);
#pragma unroll
    for (int j = 0; j < 8; ++j) {
      short8 bfv = *(const short8*)(ScTg + (long)ci * 16384 + (16 * j + l16) * 128 + kk * 32 + quad * 8);
      acc[j] = __builtin_amdgcn_mfma_f32_16x16x32_bf16(af, bfv, acc[j], 0, 0, 0);
    }
  }
#pragma unroll
  for (int kk = 0; kk < 2; ++kk) {
    short8 af = *(const short8*)(Pm + (long)ci * 4096 + (16 * wave + l16) * 64 + kk * 32 + quad * 8);
#pragma unroll
    for (int j = 0; j < 8; ++j) {
      short8 bfv = *(const short8*)(UTg + (long)ci * 8192 + (16 * j + l16) * 64 + kk * 32 + quad * 8);
      acc[j] = __builtin_amdgcn_mfma_f32_16x16x32_bf16(af, bfv, acc[j], 0, 0, 0);
    }
  }
#pragma unroll
  for (int j = 0; j < 8; ++j)
#pragma unroll
    for (int r = 0; r < 4; ++r) {
      int t = t0 + 16 * wave + quad * 4 + r;
      int n = 16 * j + l16;
      obuf[((long)(b * T_ + t) * HV_ + hv) * DV_ + n] = acc[j][r];
    }
}

// ---------------- gated RMSNorm * silu(z), cast to bf16 ----------------
__global__ __launch_bounds__(64) void rms_gate(const float* __restrict__ obuf,
                                               const float* __restrict__ zbuf,
                                               const float* __restrict__ nw,
                                               short* __restrict__ obf) {
  int bi = blockIdx.x;
  int hv = bi & 15;
  int bt = bi >> 4;
  int lane = threadIdx.x;
  const float* o = obuf + ((long)bt * HV_ + hv) * DV_;
  float2 ov = *(const float2*)(o + lane * 2);
  float ss = ov.x * ov.x + ov.y * ov.y;
#pragma unroll
  for (int m = 32; m; m >>= 1) ss += __shfl_xor(ss, m, 64);
  float scale = rsqrtf(ss * (1.f / 128.f) + 1e-6f);
  float2 wv = *(const float2*)(nw + lane * 2);
  const float* z = zbuf + (long)bt * VALUE_DIM_ + hv * DV_;
  float2 zv = *(const float2*)(z + lane * 2);
  float s0 = zv.x * (1.f / (1.f + __expf(-zv.x)));
  float s1 = zv.y * (1.f / (1.f + __expf(-zv.y)));
  short2 r;
  r.x = f2bf(ov.x * scale * wv.x * s0);
  r.y = f2bf(ov.y * scale * wv.y * s1);
  ((short2*)(obf + ((long)bt * VALUE_DIM_ + hv * DV_)))[lane] = r;
}

// ---------------- launcher ----------------
extern "C" void kernel_launch(void* const* d_in, const int* in_sizes, int n_in,
                              void* d_out, int out_size, void* d_ws, size_t ws_size,
                              hipStream_t stream) {
  const float* hidden  = (const float*)d_in[0];
  const float* W_qkv   = (const float*)d_in[1];
  const float* W_z     = (const float*)d_in[2];
  const float* W_b     = (const float*)d_in[3];
  const float* W_a     = (const float*)d_in[4];
  const float* conv_w  = (const float*)d_in[5];
  const float* dt_bias = (const float*)d_in[6];
  const float* A_log   = (const float*)d_in[7];
  const float* norm_w  = (const float*)d_in[8];
  const float* W_out   = (const float*)d_in[9];
  float* out = (float*)d_out;

  char* ws = (char*)d_ws;
  size_t off = 0;
  auto alloc = [&](size_t bytes) {
    void* p = ws + off;
    off += (bytes + 255) & ~(size_t)255;
    return p;
  };
  short* hidden_bf = (short*)alloc((size_t)BT_ * D_ * 2);           // 8 MB
  short* WqkvT     = (short*)alloc((size_t)CONV_DIM_ * D_ * 2);     // 16 MB
  short* WzT       = (short*)alloc((size_t)VALUE_DIM_ * D_ * 2);    // 8 MB
  short* WoutT     = (short*)alloc((size_t)D_ * VALUE_DIM_ * 2);    // 8 MB
  float* mixed     = (float*)alloc((size_t)BT_ * CONV_DIM_ * 4);    // 32 MB
  float* qkv       = (float*)alloc((size_t)BT_ * CONV_DIM_ * 4);    // 32 MB
  float* zbuf      = (float*)alloc((size_t)BT_ * VALUE_DIM_ * 4);   // 16 MB
  short* qbf       = (short*)alloc((size_t)BT_ * KEY_DIM_ * 2);     // 4 MB
  short* kbf       = (short*)alloc((size_t)BT_ * KEY_DIM_ * 2);     // 4 MB
  float* betab     = (float*)alloc((size_t)BT_ * HV_ * 4);
  float* gb        = (float*)alloc((size_t)BT_ * HV_ * 4);
  float* WbaT      = (float*)alloc((size_t)32 * D_ * 4);            // 256 KB
  short* Wneg      = (short*)alloc((size_t)512 * 8192 * 2);         // 8 MB
  float* Ut32      = (float*)alloc((size_t)512 * 8192 * 4);         // 16 MB
  short* KtT       = (short*)alloc((size_t)512 * 8192 * 2);         // 8 MB
  short* UTg       = (short*)alloc((size_t)512 * 8192 * 2);         // 8 MB
  short* ScTg      = (short*)alloc((size_t)512 * 16384 * 2);        // 16 MB
  float* Gammac    = (float*)alloc((size_t)512 * 4);
  // aliases into mixed (dead after conv_silu):
  float* obuf = mixed;                                 // 16 MB (phase3 out)
  short* Pm   = (short*)(mixed + (size_t)BT_ * VALUE_DIM_);         // 4 MB
  short* GQ   = Pm + (size_t)512 * 4096;                            // 8 MB
  short* obf  = hidden_bf;   // dead after gemm(z)

  dim3 tb32(32, 8);
  cast_plain<<<(BT_ * D_ / 4 + 255) / 256, 256, 0, stream>>>(hidden, hidden_bf, BT_ * D_ / 4);
  transpose_cast<<<dim3(CONV_DIM_ / 32, D_ / 32), tb32, 0, stream>>>(W_qkv, WqkvT, D_, CONV_DIM_);
  transpose_cast<<<dim3(VALUE_DIM_ / 32, D_ / 32), tb32, 0, stream>>>(W_z, WzT, D_, VALUE_DIM_);
  transpose_cast<<<dim3(D_ / 32, VALUE_DIM_ / 32), tb32, 0, stream>>>(W_out, WoutT, VALUE_DIM_, D_);
  transpose_ba<<<32 * D_ / 256, 256, 0, stream>>>(W_b, W_a, WbaT);

  gemm128<<<dim3(CONV_DIM_ / 128, BT_ / 128), 256, 0, stream>>>(hidden_bf, WqkvT, mixed, BT_, CONV_DIM_, D_);
  gemm128<<<dim3(VALUE_DIM_ / 128, BT_ / 128), 256, 0, stream>>>(hidden_bf, WzT, zbuf, BT_, VALUE_DIM_, D_);
  small_proj<<<BT_, 256, 0, stream>>>(hidden, WbaT, dt_bias, A_log, betab, gb);
  conv_silu<<<BT_ * CONV_DIM_ / 256, 256, 0, stream>>>(mixed, conv_w, qkv);
  qknorm<<<BT_ * HK_ * 2, 64, 0, stream>>>(qkv, qbf, kbf);

  chunk_phase1<<<512, 256, 0, stream>>>(qbf, kbf, qkv, gb, betab, Pm, GQ, KtT, Wneg, Ut32, Gammac);
  chunk_phase2<<<64, 256, 0, stream>>>(Wneg, Ut32, KtT, Gammac, UTg, ScTg);
  chunk_phase3<<<512, 256, 0, stream>>>(GQ, ScTg, Pm, UTg, obuf);

  rms_gate<<<BT_ * HV_, 64, 0, stream>>>(obuf, zbuf, norm_w, obf);
  gemm128<<<dim3(D_ / 128, BT_ / 128), 256, 0, stream>>>(obf, WoutT, out, BT_, D_, VALUE_DIM_);
}

// Round 6
// 461.344 us; speedup vs baseline: 1.5521x; 1.1429x over previous
//
#include <hip/hip_runtime.h>
#include <hip/hip_bf16.h>

// GatedDeltaNet: B=2, T=1024, D=2048, HK=8, HV=16, DK=DV=128, KW=4
#define B_ 2
#define T_ 1024
#define D_ 2048
#define HK_ 8
#define HV_ 16
#define DK_ 128
#define DV_ 128
#define KEY_DIM_ 1024
#define VALUE_DIM_ 2048
#define CONV_DIM_ 4096
#define BT_ 2048   // B*T
#define NCH_ 16    // chunks per sequence (T/64)
#define CL_ 64     // chunk length

typedef __attribute__((ext_vector_type(8))) short short8;
typedef __attribute__((ext_vector_type(4))) float f32x4;

__device__ __forceinline__ short f2bf(float x) {
  __hip_bfloat16 h = __float2bfloat16(x);
  return *reinterpret_cast<short*>(&h);
}
__device__ __forceinline__ float bf2f(short u) {
  unsigned int x = ((unsigned int)(unsigned short)u) << 16;
  return __int_as_float(x);
}

#define GLOAD_LDS16(g, l)                                             \
  __builtin_amdgcn_global_load_lds(                                   \
      (const __attribute__((address_space(1))) void*)(g),             \
      (__attribute__((address_space(3))) void*)(l), 16, 0, 0)

// ---------------- cast f32 -> bf16 ----------------
__global__ void cast_plain(const float* __restrict__ in, short* __restrict__ out, int n4) {
  int i = blockIdx.x * blockDim.x + threadIdx.x;
  if (i < n4) {
    float4 v = ((const float4*)in)[i];
    short4 o;
    o.x = f2bf(v.x); o.y = f2bf(v.y); o.z = f2bf(v.z); o.w = f2bf(v.w);
    ((short4*)out)[i] = o;
  }
}

// ---------------- transpose + cast: W[R,C] f32 -> WT[C,R] bf16 ----------------
__global__ void transpose_cast(const float* __restrict__ W, short* __restrict__ WT, int R, int C) {
  __shared__ float tile[32][33];
  int tx = threadIdx.x, ty = threadIdx.y;
  int x = blockIdx.x * 32 + tx;
#pragma unroll
  for (int j = 0; j < 4; ++j) {
    int r = blockIdx.y * 32 + ty + j * 8;
    tile[ty + j * 8][tx] = W[(long)r * C + x];
  }
  __syncthreads();
  int ro = blockIdx.y * 32 + tx;
#pragma unroll
  for (int j = 0; j < 4; ++j) {
    int co = blockIdx.x * 32 + ty + j * 8;
    WT[(long)co * R + ro] = f2bf(tile[tx][ty + j * 8]);
  }
}

// ---------------- W_b|W_a -> Wba32[k][32] (k-major interleave) ----------------
__global__ void interleave_ba(const float* __restrict__ Wb, const float* __restrict__ Wa,
                              float* __restrict__ Wba32) {
  int i = blockIdx.x * 256 + threadIdx.x;   // D*32
  int c = i & 31, k = i >> 5;
  Wba32[i] = (c < 16) ? Wb[k * 16 + c] : Wa[k * 16 + (c - 16)];
}

// ---------------- bf16 MFMA GEMM (m97-style) ----------------
__global__ __launch_bounds__(256) void gemm128(const short* __restrict__ A,
                                               const short* __restrict__ Bt,
                                               float* __restrict__ C,
                                               int M, int N, int K) {
  __shared__ short As[128 * 32];
  __shared__ short Bs[128 * 32];
  int m0 = blockIdx.y * 128, n0 = blockIdx.x * 128;
  int tid = threadIdx.x;
  int wave = tid >> 6, lane = tid & 63;
  int wm = (wave >> 1) * 64, wn = (wave & 1) * 64;
  int quad = lane >> 4, l16 = lane & 15;
  f32x4 acc[4][4] = {};

  int ar = tid >> 2;
  int ac = (tid & 3) * 8;
  const short* Ag0 = A + (long)(m0 + ar) * K + ac;
  const short* Ag1 = A + (long)(m0 + 64 + ar) * K + ac;
  const short* Bg0 = Bt + (long)(n0 + ar) * K + ac;
  const short* Bg1 = Bt + (long)(n0 + 64 + ar) * K + ac;
  short* lA0 = As + tid * 8;
  short* lA1 = As + 64 * 32 + tid * 8;
  short* lB0 = Bs + tid * 8;
  short* lB1 = Bs + 64 * 32 + tid * 8;

  for (int k0 = 0; k0 < K; k0 += 32) {
    GLOAD_LDS16(Ag0 + k0, lA0);
    GLOAD_LDS16(Ag1 + k0, lA1);
    GLOAD_LDS16(Bg0 + k0, lB0);
    GLOAD_LDS16(Bg1 + k0, lB1);
    __syncthreads();

    short8 af[4], bf_[4];
#pragma unroll
    for (int i = 0; i < 4; ++i) af[i] = *(const short8*)(As + (wm + i * 16 + l16) * 32 + quad * 8);
#pragma unroll
    for (int j = 0; j < 4; ++j) bf_[j] = *(const short8*)(Bs + (wn + j * 16 + l16) * 32 + quad * 8);
#pragma unroll
    for (int i = 0; i < 4; ++i)
#pragma unroll
      for (int j = 0; j < 4; ++j)
        acc[i][j] = __builtin_amdgcn_mfma_f32_16x16x32_bf16(af[i], bf_[j], acc[i][j], 0, 0, 0);
    __syncthreads();
  }

#pragma unroll
  for (int i = 0; i < 4; ++i)
#pragma unroll
    for (int j = 0; j < 4; ++j)
#pragma unroll
      for (int r = 0; r < 4; ++r) {
        int row = m0 + wm + i * 16 + quad * 4 + r;
        int colx = n0 + wn + j * 16 + l16;
        C[(long)row * N + colx] = acc[i][j][r];
      }
}

// ---------------- beta / g projections (fp32, coalesced mini-GEMM) -----------
// grid 1024: 2 rows/block. Thread (cg=tid&7 -> 4 cols, s=tid>>3 -> 64-k slice).
// W-loads lane-consecutive float4; hidden loads per-thread float4.
__global__ __launch_bounds__(256) void small_proj(const float* __restrict__ hidden,
                                                  const float* __restrict__ Wba32,
                                                  const float* __restrict__ dt_bias,
                                                  const float* __restrict__ A_log,
                                                  float* __restrict__ betaT,
                                                  float* __restrict__ gT) {
  __shared__ float red[2][32][33];
  int r0 = blockIdx.x * 2;
  int tid = threadIdx.x;
  int cg = tid & 7, s = tid >> 3;
  const f32x4* wp = (const f32x4*)Wba32 + (long)s * 64 * 8 + cg;
  const f32x4* h0 = (const f32x4*)(hidden + (long)r0 * D_ + s * 64);
  const f32x4* h1 = (const f32x4*)(hidden + (long)(r0 + 1) * D_ + s * 64);
  f32x4 a0 = {0.f, 0.f, 0.f, 0.f}, a1 = {0.f, 0.f, 0.f, 0.f};
#pragma unroll
  for (int ii = 0; ii < 16; ++ii) {
    f32x4 ha = h0[ii], hb = h1[ii];
    f32x4 w0 = wp[(ii * 4 + 0) * 8];
    f32x4 w1 = wp[(ii * 4 + 1) * 8];
    f32x4 w2 = wp[(ii * 4 + 2) * 8];
    f32x4 w3 = wp[(ii * 4 + 3) * 8];
    a0 += ha[0] * w0; a1 += hb[0] * w0;
    a0 += ha[1] * w1; a1 += hb[1] * w1;
    a0 += ha[2] * w2; a1 += hb[2] * w2;
    a0 += ha[3] * w3; a1 += hb[3] * w3;
  }
#pragma unroll
  for (int j = 0; j < 4; ++j) {
    red[0][s][cg * 4 + j] = a0[j];
    red[1][s][cg * 4 + j] = a1[j];
  }
  __syncthreads();
  if (tid < 64) {
    int row = tid >> 5, c = tid & 31;
    float t0 = 0.f, t1 = 0.f, t2 = 0.f, t3 = 0.f;
#pragma unroll
    for (int ss = 0; ss < 32; ss += 4) {
      t0 += red[row][ss][c];
      t1 += red[row][ss + 1][c];
      t2 += red[row][ss + 2][c];
      t3 += red[row][ss + 3][c];
    }
    float t = (t0 + t1) + (t2 + t3);
    int r = r0 + row;
    if (c < 16) {
      betaT[c * BT_ + r] = 1.f / (1.f + __expf(-t));
    } else {
      int hh = c - 16;
      float y = t + dt_bias[hh];
      float sp = fmaxf(y, 0.f) + log1pf(__expf(-fabsf(y)));
      gT[hh * BT_ + r] = -__expf(A_log[hh]) * sp;   // raw g (log decay)
    }
  }
}

// ---------------- depthwise causal conv (K=4) + SiLU ----------------
__global__ void conv_silu(const float* __restrict__ x, const float* __restrict__ w,
                          float* __restrict__ y) {
  int idx = blockIdx.x * 256 + threadIdx.x;
  int c = idx & (CONV_DIM_ - 1);
  int bt = idx >> 12;
  int t = bt & (T_ - 1);
  float4 wc = *(const float4*)(w + c * 4);
  const float* xp = x + (long)idx;
  float acc = wc.w * xp[0];
  if (t >= 1) acc += wc.z * xp[-CONV_DIM_];
  if (t >= 2) acc += wc.y * xp[-2 * CONV_DIM_];
  if (t >= 3) acc += wc.x * xp[-3 * CONV_DIM_];
  y[idx] = acc * (1.f / (1.f + __expf(-acc)));
}

// ---------------- q/k l2norm (+ q scale), bf16 out ----------------
__global__ __launch_bounds__(64) void qknorm(const float* __restrict__ qkv,
                                             short* __restrict__ qb, short* __restrict__ kb) {
  int bi = blockIdx.x;          // B*T*HK*2
  int which = bi & 1;
  int h = (bi >> 1) & 7;
  int bt = bi >> 4;
  int lane = threadIdx.x;
  const float* src = qkv + (long)bt * CONV_DIM_ + which * KEY_DIM_ + h * DK_;
  float2 v = *(const float2*)(src + lane * 2);
  float ss = v.x * v.x + v.y * v.y;
#pragma unroll
  for (int m = 32; m; m >>= 1) ss += __shfl_xor(ss, m, 64);
  float scale = rsqrtf(ss + 1e-6f);
  if (which == 0) scale *= 0.08838834764831845f;  // DK^-0.5
  short* dst = (which ? kb : qb) + ((long)bt * HK_ + h) * DK_;
  short2 o; o.x = f2bf(v.x * scale); o.y = f2bf(v.y * scale);
  ((short2*)dst)[lane] = o;
}

// ================= PHASE 1: per-chunk local quantities (parallel, 512 blocks)
__global__ __launch_bounds__(256, 2) void chunk_phase1(
    const short* __restrict__ qbf, const short* __restrict__ kbf,
    const float* __restrict__ qkv, const float* __restrict__ gT,
    const float* __restrict__ bT,
    short* __restrict__ Pm, short* __restrict__ GQ, short* __restrict__ KtT,
    short* __restrict__ Wneg, float* __restrict__ Ut, float* __restrict__ Gammac) {
  __shared__ float Al[64 * 64];      // 16 KB
  __shared__ float Gs[64], Gam[64], Dd[64], Bet[64], BG[64];

  int ci = blockIdx.x;
  int c = ci & 15, hv = (ci >> 4) & 15, b = ci >> 8;
  int hk = hv >> 1;
  int t0 = c * CL_;
  int tid = threadIdx.x;
  int wave = tid >> 6, lane = tid & 63, quad = lane >> 4, l16 = lane & 15;

  if (tid < 64) {
    float g = gT[(hv * B_ + b) * T_ + t0 + tid];
    float x = g;
#pragma unroll
    for (int off = 1; off < 64; off <<= 1) {
      float y = __shfl_up(x, off, 64);
      if (tid >= off) x += y;
    }
    Gs[tid] = x;
    float gm = __expf(x);
    Gam[tid] = gm;
    float Gtot = __shfl(x, 63, 64);
    Dd[tid] = __expf(Gtot - x);
    float bb = bT[(hv * B_ + b) * T_ + t0 + tid];
    Bet[tid] = bb;
    BG[tid] = bb * gm;
    if (tid == 63) Gammac[ci] = __expf(x);
  }
  __syncthreads();

  const long kbase = ((long)(b * T_ + t0) * HK_ + hk) * DK_;   // in shorts
  const int kstride = HK_ * DK_;                               // 1024

  // ---- RHS columns into registers (coalesced: lane-consecutive cols) ----
  int half = tid >> 7;        // 0 = V-columns, 1 = betaGammaK-columns
  int col = tid & 127;
  float u[64];
  {
    const float* vcol = qkv + (long)(b * T_ + t0) * CONV_DIM_ + 2 * KEY_DIM_ + hv * DV_ + col;
    const short* kcol = kbf + kbase + col;
    if (half == 0) {
#pragma unroll
      for (int r = 0; r < 64; ++r) u[r] = vcol[(long)r * CONV_DIM_];
    } else {
#pragma unroll
      for (int r = 0; r < 64; ++r) u[r] = bf2f(kcol[(long)r * kstride]);
    }
  }

  // ---- KK^T -> Al (mask s>r, scale beta_s * exp(G_s - G_r)) ----
  {
    f32x4 acc[4] = {};
#pragma unroll
    for (int kk = 0; kk < 4; ++kk) {
      short8 afr = *(const short8*)(kbf + kbase + (long)(16 * wave + l16) * kstride + kk * 32 + quad * 8);
#pragma unroll
      for (int j = 0; j < 4; ++j) {
        short8 bfr = *(const short8*)(kbf + kbase + (long)(16 * j + l16) * kstride + kk * 32 + quad * 8);
        acc[j] = __builtin_amdgcn_mfma_f32_16x16x32_bf16(afr, bfr, acc[j], 0, 0, 0);
      }
    }
#pragma unroll
    for (int j = 0; j < 4; ++j)
#pragma unroll
      for (int r = 0; r < 4; ++r) {
        int row = 16 * wave + quad * 4 + r, colx = 16 * j + l16;
        float v = 0.f;
        if (row > colx) v = Bet[row] * __expf(Gs[row] - Gs[colx]) * acc[j][r];
        Al[row * 64 + colx] = v;
      }
  }
  // ---- QK^T -> Pm (mask t>=s, scale exp(G_t - G_s)) ----
  {
    f32x4 acc[4] = {};
#pragma unroll
    for (int kk = 0; kk < 4; ++kk) {
      short8 afr = *(const short8*)(qbf + kbase + (long)(16 * wave + l16) * kstride + kk * 32 + quad * 8);
#pragma unroll
      for (int j = 0; j < 4; ++j) {
        short8 bfr = *(const short8*)(kbf + kbase + (long)(16 * j + l16) * kstride + kk * 32 + quad * 8);
        acc[j] = __builtin_amdgcn_mfma_f32_16x16x32_bf16(afr, bfr, acc[j], 0, 0, 0);
      }
    }
#pragma unroll
    for (int j = 0; j < 4; ++j)
#pragma unroll
      for (int r = 0; r < 4; ++r) {
        int row = 16 * wave + quad * 4 + r, colx = 16 * j + l16;
        float v = 0.f;
        if (row >= colx) v = __expf(Gs[row] - Gs[colx]) * acc[j][r];
        Pm[(long)ci * 4096 + row * 64 + colx] = f2bf(v);
      }
  }
  // ---- GQ[s][d] = Gam[s]*q[s][d] (coalesced short2 writes) ----
  for (int s = wave; s < 64; s += 4) {
    float gm = Gam[s];
    short2 qv = *(const short2*)(qbf + kbase + (long)s * kstride + lane * 2);
    short2 o;
    o.x = f2bf(bf2f(qv.x) * gm);
    o.y = f2bf(bf2f(qv.y) * gm);
    *(short2*)(GQ + (long)ci * 8192 + s * 128 + lane * 2) = o;
  }
  // ---- KtT[d][s] = k[s][d]*Dd[s] ----
  for (int d = wave; d < 128; d += 4) {
    float kv = bf2f(kbf[kbase + (long)lane * kstride + d]);
    KtT[(long)ci * 8192 + d * 64 + lane] = f2bf(kv * Dd[lane]);
  }
  __syncthreads();   // Al complete

  // ---- scale RHS, register-resident forward substitution ----
  if (half == 0) {
#pragma unroll
    for (int r = 0; r < 64; ++r) u[r] *= Bet[r];
  } else {
#pragma unroll
    for (int r = 0; r < 64; ++r) u[r] *= BG[r];
  }
#pragma unroll
  for (int s = 1; s < 64; ++s) {
    const float* Ar = Al + s * 64;
    float acc = 0.f;
#pragma unroll
    for (int r4 = 0; r4 + 4 <= s; r4 += 4) {
      float4 a = *(const float4*)(Ar + r4);
      acc += (a.x * u[r4] + a.y * u[r4 + 1]) + (a.z * u[r4 + 2] + a.w * u[r4 + 3]);
    }
#pragma unroll
    for (int r = (s / 4) * 4; r < s; ++r) acc += Ar[r] * u[r];
    u[s] -= acc;
  }
  // ---- write out (coalesced) ----
  if (half == 0) {
    float* up = Ut + (long)ci * 8192 + col;
#pragma unroll
    for (int s = 0; s < 64; ++s) up[s * 128] = u[s];
  } else {
    short* wp = Wneg + (long)ci * 8192 + col;
#pragma unroll
    for (int s = 0; s < 64; ++s) wp[s * 128] = f2bf(-u[s]);
  }
}

// ================= PHASE 2: state recurrence over chunks (64 blocks) =========
__global__ __launch_bounds__(256) void chunk_phase2(
    const short* __restrict__ Wneg, const float* __restrict__ Ut,
    const short* __restrict__ KtT, const float* __restrict__ Gammac,
    short* __restrict__ UTg, short* __restrict__ ScTg) {
  __shared__ short SLT[64 * 136];   // S^T half [n 64][m 128 pad 136], 17 KB
  __shared__ short ULT[64 * 72];    // U^T half [n 64][s 64 pad 72], 9 KB
  int bi = blockIdx.x >> 1;          // b*16+hv
  int n0 = (blockIdx.x & 1) * 64;    // col-half base
  int tid = threadIdx.x, wave = tid >> 6, lane = tid & 63, quad = lane >> 4, l16 = lane & 15;
  f32x4 S[2][4] = {};   // rows 32*wave+16i+quad*4, cols n0+16j+l16

  for (int ch = 0; ch < NCH_; ++ch) {
    long ci = (long)bi * NCH_ + ch;
#pragma unroll
    for (int i = 0; i < 2; ++i)
#pragma unroll
      for (int j = 0; j < 4; ++j) {
        int m0 = 32 * wave + 16 * i + quad * 4;
        int n = 16 * j + l16;
        short4 p;
        p.x = f2bf(S[i][j][0]); p.y = f2bf(S[i][j][1]);
        p.z = f2bf(S[i][j][2]); p.w = f2bf(S[i][j][3]);
        *(short4*)(SLT + n * 136 + m0) = p;
        *(short4*)(ScTg + ci * 16384 + (n0 + n) * 128 + m0) = p;
      }
    __syncthreads();
    f32x4 Ua[4];
#pragma unroll
    for (int j = 0; j < 4; ++j) {
      const float* up = Ut + ci * 8192 + (16 * wave + quad * 4) * 128 + n0 + 16 * j + l16;
#pragma unroll
      for (int r = 0; r < 4; ++r) Ua[j][r] = up[r * 128];
    }
#pragma unroll
    for (int kk = 0; kk < 4; ++kk) {
      short8 af = *(const short8*)(Wneg + ci * 8192 + (16 * wave + l16) * 128 + kk * 32 + quad * 8);
#pragma unroll
      for (int j = 0; j < 4; ++j) {
        short8 bfv = *(const short8*)(SLT + (16 * j + l16) * 136 + kk * 32 + quad * 8);
        Ua[j] = __builtin_amdgcn_mfma_f32_16x16x32_bf16(af, bfv, Ua[j], 0, 0, 0);
      }
    }
#pragma unroll
    for (int j = 0; j < 4; ++j) {
      int n = 16 * j + l16, s0q = 16 * wave + quad * 4;
      short4 p;
      p.x = f2bf(Ua[j][0]); p.y = f2bf(Ua[j][1]);
      p.z = f2bf(Ua[j][2]); p.w = f2bf(Ua[j][3]);
      *(short4*)(ULT + n * 72 + s0q) = p;
      *(short4*)(UTg + ci * 8192 + (n0 + n) * 64 + s0q) = p;
    }
    __syncthreads();
    float gc = Gammac[ci];
#pragma unroll
    for (int i = 0; i < 2; ++i)
#pragma unroll
      for (int j = 0; j < 4; ++j)
#pragma unroll
        for (int r = 0; r < 4; ++r) S[i][j][r] *= gc;
#pragma unroll
    for (int kk = 0; kk < 2; ++kk)
#pragma unroll
      for (int i = 0; i < 2; ++i) {
        short8 af = *(const short8*)(KtT + ci * 8192 + (32 * wave + 16 * i + l16) * 64 + kk * 32 + quad * 8);
#pragma unroll
        for (int j = 0; j < 4; ++j) {
          short8 bfv = *(const short8*)(ULT + (16 * j + l16) * 72 + kk * 32 + quad * 8);
          S[i][j] = __builtin_amdgcn_mfma_f32_16x16x32_bf16(af, bfv, S[i][j], 0, 0, 0);
        }
      }
    __syncthreads();
  }
}

// ================= PHASE 3: outputs (parallel, 512 blocks) ===================
__global__ __launch_bounds__(256) void chunk_phase3(
    const short* __restrict__ GQ, const short* __restrict__ ScTg,
    const short* __restrict__ Pm, const short* __restrict__ UTg,
    float* __restrict__ obuf) {
  int ci = blockIdx.x;
  int c = ci & 15, hv = (ci >> 4) & 15, b = ci >> 8;
  int t0 = c * CL_;
  int tid = threadIdx.x, wave = tid >> 6, lane = tid & 63, quad = lane >> 4, l16 = lane & 15;
  f32x4 acc[8] = {};
#pragma unroll
  for (int kk = 0; kk < 4; ++kk) {
    short8 af = *(const short8*)(GQ + (long)ci * 8192 + (16 * wave + l16) * 128 + kk * 32 + quad * 8);
#pragma unroll
    for (int j = 0; j < 8; ++j) {
      short8 bfv = *(const short8*)(ScTg + (long)ci * 16384 + (16 * j + l16) * 128 + kk * 32 + quad * 8);
      acc[j] = __builtin_amdgcn_mfma_f32_16x16x32_bf16(af, bfv, acc[j], 0, 0, 0);
    }
  }
#pragma unroll
  for (int kk = 0; kk < 2; ++kk) {
    short8 af = *(const short8*)(Pm + (long)ci * 4096 + (16 * wave + l16) * 64 + kk * 32 + quad * 8);
#pragma unroll
    for (int j = 0; j < 8; ++j) {
      short8 bfv = *(const short8*)(UTg + (long)ci * 8192 + (16 * j + l16) * 64 + kk * 32 + quad * 8);
      acc[j] = __builtin_amdgcn_mfma_f32_16x16x32_bf16(af, bfv, acc[j], 0, 0, 0);
    }
  }
#pragma unroll
  for (int j = 0; j < 8; ++j)
#pragma unroll
    for (int r = 0; r < 4; ++r) {
      int t = t0 + 16 * wave + quad * 4 + r;
      int n = 16 * j + l16;
      obuf[((long)(b * T_ + t) * HV_ + hv) * DV_ + n] = acc[j][r];
    }
}

// ---------------- gated RMSNorm * silu(z), cast to bf16 ----------------
__global__ __launch_bounds__(64) void rms_gate(const float* __restrict__ obuf,
                                               const float* __restrict__ zbuf,
                                               const float* __restrict__ nw,
                                               short* __restrict__ obf) {
  int bi = blockIdx.x;
  int hv = bi & 15;
  int bt = bi >> 4;
  int lane = threadIdx.x;
  const float* o = obuf + ((long)bt * HV_ + hv) * DV_;
  float2 ov = *(const float2*)(o + lane * 2);
  float ss = ov.x * ov.x + ov.y * ov.y;
#pragma unroll
  for (int m = 32; m; m >>= 1) ss += __shfl_xor(ss, m, 64);
  float scale = rsqrtf(ss * (1.f / 128.f) + 1e-6f);
  float2 wv = *(const float2*)(nw + lane * 2);
  const float* z = zbuf + (long)bt * VALUE_DIM_ + hv * DV_;
  float2 zv = *(const float2*)(z + lane * 2);
  float s0 = zv.x * (1.f / (1.f + __expf(-zv.x)));
  float s1 = zv.y * (1.f / (1.f + __expf(-zv.y)));
  short2 r;
  r.x = f2bf(ov.x * scale * wv.x * s0);
  r.y = f2bf(ov.y * scale * wv.y * s1);
  ((short2*)(obf + ((long)bt * VALUE_DIM_ + hv * DV_)))[lane] = r;
}

// ---------------- launcher ----------------
extern "C" void kernel_launch(void* const* d_in, const int* in_sizes, int n_in,
                              void* d_out, int out_size, void* d_ws, size_t ws_size,
                              hipStream_t stream) {
  const float* hidden  = (const float*)d_in[0];
  const float* W_qkv   = (const float*)d_in[1];
  const float* W_z     = (const float*)d_in[2];
  const float* W_b     = (const float*)d_in[3];
  const float* W_a     = (const float*)d_in[4];
  const float* conv_w  = (const float*)d_in[5];
  const float* dt_bias = (const float*)d_in[6];
  const float* A_log   = (const float*)d_in[7];
  const float* norm_w  = (const float*)d_in[8];
  const float* W_out   = (const float*)d_in[9];
  float* out = (float*)d_out;

  char* ws = (char*)d_ws;
  size_t off = 0;
  auto alloc = [&](size_t bytes) {
    void* p = ws + off;
    off += (bytes + 255) & ~(size_t)255;
    return p;
  };
  short* hidden_bf = (short*)alloc((size_t)BT_ * D_ * 2);           // 8 MB
  short* WqkvT     = (short*)alloc((size_t)CONV_DIM_ * D_ * 2);     // 16 MB
  short* WzT       = (short*)alloc((size_t)VALUE_DIM_ * D_ * 2);    // 8 MB
  short* WoutT     = (short*)alloc((size_t)D_ * VALUE_DIM_ * 2);    // 8 MB
  float* mixed     = (float*)alloc((size_t)BT_ * CONV_DIM_ * 4);    // 32 MB
  float* qkv       = (float*)alloc((size_t)BT_ * CONV_DIM_ * 4);    // 32 MB
  float* zbuf      = (float*)alloc((size_t)BT_ * VALUE_DIM_ * 4);   // 16 MB
  short* qbf       = (short*)alloc((size_t)BT_ * KEY_DIM_ * 2);     // 4 MB
  short* kbf       = (short*)alloc((size_t)BT_ * KEY_DIM_ * 2);     // 4 MB
  float* betab     = (float*)alloc((size_t)BT_ * HV_ * 4);
  float* gb        = (float*)alloc((size_t)BT_ * HV_ * 4);
  float* Wba32     = (float*)alloc((size_t)D_ * 32 * 4);            // 256 KB
  short* Wneg      = (short*)alloc((size_t)512 * 8192 * 2);         // 8 MB
  float* Ut32      = (float*)alloc((size_t)512 * 8192 * 4);         // 16 MB
  short* KtT       = (short*)alloc((size_t)512 * 8192 * 2);         // 8 MB
  short* UTg       = (short*)alloc((size_t)512 * 8192 * 2);         // 8 MB
  short* ScTg      = (short*)alloc((size_t)512 * 16384 * 2);        // 16 MB
  float* Gammac    = (float*)alloc((size_t)512 * 4);
  // aliases into mixed (dead after conv_silu):
  float* obuf = mixed;                                 // 16 MB (phase3 out)
  short* Pm   = (short*)(mixed + (size_t)BT_ * VALUE_DIM_);         // 4 MB
  short* GQ   = Pm + (size_t)512 * 4096;                            // 8 MB
  short* obf  = hidden_bf;   // dead after gemm(z)

  dim3 tb32(32, 8);
  cast_plain<<<(BT_ * D_ / 4 + 255) / 256, 256, 0, stream>>>(hidden, hidden_bf, BT_ * D_ / 4);
  transpose_cast<<<dim3(CONV_DIM_ / 32, D_ / 32), tb32, 0, stream>>>(W_qkv, WqkvT, D_, CONV_DIM_);
  transpose_cast<<<dim3(VALUE_DIM_ / 32, D_ / 32), tb32, 0, stream>>>(W_z, WzT, D_, VALUE_DIM_);
  transpose_cast<<<dim3(D_ / 32, VALUE_DIM_ / 32), tb32, 0, stream>>>(W_out, WoutT, VALUE_DIM_, D_);
  interleave_ba<<<32 * D_ / 256, 256, 0, stream>>>(W_b, W_a, Wba32);

  gemm128<<<dim3(CONV_DIM_ / 128, BT_ / 128), 256, 0, stream>>>(hidden_bf, WqkvT, mixed, BT_, CONV_DIM_, D_);
  gemm128<<<dim3(VALUE_DIM_ / 128, BT_ / 128), 256, 0, stream>>>(hidden_bf, WzT, zbuf, BT_, VALUE_DIM_, D_);
  small_proj<<<BT_ / 2, 256, 0, stream>>>(hidden, Wba32, dt_bias, A_log, betab, gb);
  conv_silu<<<BT_ * CONV_DIM_ / 256, 256, 0, stream>>>(mixed, conv_w, qkv);
  qknorm<<<BT_ * HK_ * 2, 64, 0, stream>>>(qkv, qbf, kbf);

  chunk_phase1<<<512, 256, 0, stream>>>(qbf, kbf, qkv, gb, betab, Pm, GQ, KtT, Wneg, Ut32, Gammac);
  chunk_phase2<<<64, 256, 0, stream>>>(Wneg, Ut32, KtT, Gammac, UTg, ScTg);
  chunk_phase3<<<512, 256, 0, stream>>>(GQ, ScTg, Pm, UTg, obuf);

  rms_gate<<<BT_ * HV_, 64, 0, stream>>>(obuf, zbuf, norm_w, obf);
  gemm128<<<dim3(D_ / 128, BT_ / 128), 256, 0, stream>>>(obf, WoutT, out, BT_, D_, VALUE_DIM_);
}